// Round 1
// baseline (4819.600 us; speedup 1.0000x reference)
//
#include <hip/hip_runtime.h>
#include <math.h>

#define TPB 256
#define NF 128          // feature width (all layers)
#define BN_EPS_C 1e-5f

// ---------------------------------------------------------------------------
// fast fire-and-forget f32 atomic add (hardware global_atomic_add_f32)
// ---------------------------------------------------------------------------
__device__ __forceinline__ void atomAddF(float* p, float v) {
    unsafeAtomicAdd(p, v);   // gfx90a+: lowers to global_atomic_add_f32 (no CAS loop)
}

// ---------------------------------------------------------------------------
// Edge scatter: agg[dst] += norm(x[src]).  One 64-lane wave per edge, float2
// per lane (128 feats). NORM applies the folded BN affine (a*x + c) of the
// previous layer on the fly.
// ---------------------------------------------------------------------------
template<bool NORM>
__global__ __launch_bounds__(TPB) void scatter_kernel(
    const float* __restrict__ x, const int* __restrict__ src,
    const int* __restrict__ dst,
    const float* __restrict__ na, const float* __restrict__ nc,
    float* __restrict__ agg, int E)
{
    int gid  = blockIdx.x * TPB + threadIdx.x;
    int e    = gid >> 6;
    if (e >= E) return;
    int lane = gid & 63;
    int s = src[e];          // wave-uniform broadcast load
    int d = dst[e];
    float2 v = *(const float2*)(x + (size_t)s * NF + lane * 2);
    if (NORM) {
        float2 aa = *(const float2*)(na + lane * 2);
        float2 cc = *(const float2*)(nc + lane * 2);
        v.x = v.x * aa.x + cc.x;
        v.y = v.y * aa.y + cc.y;
    }
    float* o = agg + (size_t)d * NF + lane * 2;
    atomAddF(o,     v.x);
    atomAddF(o + 1, v.y);
}

// ---------------------------------------------------------------------------
// Dual-A GEMM: C = Aagg @ Wr + norm(Ax) @ Wroot + bias, optional ReLU.
// Tile: 64 rows x 128 cols (full N), K chunked by 16. 256 threads, each
// computes 4 rows x 8 cols. fp32 vector ALU (no fp32 MFMA on CDNA4).
// C may alias Aagg (in-place): each block writes only rows it fully consumed.
// ---------------------------------------------------------------------------
template<bool RELU, bool NORM>
__global__ __launch_bounds__(TPB) void gemm_conv(
    const float* Aagg, const float* Ax,                    // may alias C - no restrict
    const float* __restrict__ na, const float* __restrict__ nc,
    const float* __restrict__ Wr, const float* __restrict__ Wroot,
    const float* __restrict__ bias, float* C, int M)
{
    __shared__ __align__(16) float sAa[16][68];   // [k][row], pad 68: 2-way wr conflict only
    __shared__ __align__(16) float sAx[16][68];
    __shared__ __align__(16) float sWr[16][NF];   // [k][col]
    __shared__ __align__(16) float sWo[16][NF];

    const int tid = threadIdx.x;
    const int tx  = tid & 15;          // col group: cols tx*4..+3 and 64+tx*4..+3
    const int ty  = tid >> 4;          // row group: rows ty*4..+3
    const int m0  = blockIdx.x * 64;

    float acc[4][8];
#pragma unroll
    for (int i = 0; i < 4; ++i)
#pragma unroll
        for (int j = 0; j < 8; ++j) acc[i][j] = 0.f;

    const int lr = tid >> 2;           // A-load row 0..63
    const int lk = (tid & 3) * 4;      // A-load k offset 0/4/8/12
    const int wrow = tid >> 4;         // W-load row 0..15
    const int wcol = (tid & 15) * 8;   // W-load col

    for (int kc = 0; kc < NF; kc += 16) {
        // ---- global loads to registers
        int row = m0 + lr;
        float4 va = make_float4(0.f, 0.f, 0.f, 0.f);
        float4 vx = va;
        if (row < M) {
            va = *(const float4*)(Aagg + (size_t)row * NF + kc + lk);
            vx = *(const float4*)(Ax   + (size_t)row * NF + kc + lk);
        }
        if (NORM) {
            float4 a4 = *(const float4*)(na + kc + lk);
            float4 c4 = *(const float4*)(nc + kc + lk);
            vx.x = vx.x * a4.x + c4.x;  vx.y = vx.y * a4.y + c4.y;
            vx.z = vx.z * a4.z + c4.z;  vx.w = vx.w * a4.w + c4.w;
        }
        float4 w0 = *(const float4*)(Wr    + (size_t)(kc + wrow) * NF + wcol);
        float4 w1 = *(const float4*)(Wr    + (size_t)(kc + wrow) * NF + wcol + 4);
        float4 o0 = *(const float4*)(Wroot + (size_t)(kc + wrow) * NF + wcol);
        float4 o1 = *(const float4*)(Wroot + (size_t)(kc + wrow) * NF + wcol + 4);

        __syncthreads();               // previous chunk fully consumed
        sAa[lk + 0][lr] = va.x; sAa[lk + 1][lr] = va.y;
        sAa[lk + 2][lr] = va.z; sAa[lk + 3][lr] = va.w;
        sAx[lk + 0][lr] = vx.x; sAx[lk + 1][lr] = vx.y;
        sAx[lk + 2][lr] = vx.z; sAx[lk + 3][lr] = vx.w;
        *(float4*)&sWr[wrow][wcol]     = w0;
        *(float4*)&sWr[wrow][wcol + 4] = w1;
        *(float4*)&sWo[wrow][wcol]     = o0;
        *(float4*)&sWo[wrow][wcol + 4] = o1;
        __syncthreads();

#pragma unroll
        for (int kk = 0; kk < 16; ++kk) {
            float4 aa = *(const float4*)&sAa[kk][ty * 4];
            float4 ax = *(const float4*)&sAx[kk][ty * 4];
            float4 r0 = *(const float4*)&sWr[kk][tx * 4];
            float4 r1 = *(const float4*)&sWr[kk][tx * 4 + 64];
            float4 q0 = *(const float4*)&sWo[kk][tx * 4];
            float4 q1 = *(const float4*)&sWo[kk][tx * 4 + 64];
            float A_[4] = {aa.x, aa.y, aa.z, aa.w};
            float X_[4] = {ax.x, ax.y, ax.z, ax.w};
            float R_[8] = {r0.x, r0.y, r0.z, r0.w, r1.x, r1.y, r1.z, r1.w};
            float Q_[8] = {q0.x, q0.y, q0.z, q0.w, q1.x, q1.y, q1.z, q1.w};
#pragma unroll
            for (int i = 0; i < 4; ++i)
#pragma unroll
                for (int j = 0; j < 8; ++j)
                    acc[i][j] += A_[i] * R_[j] + X_[i] * Q_[j];
        }
    }

    // ---- epilogue: bias (+ReLU), coalesced float4 stores
    float4 b0 = *(const float4*)(bias + tx * 4);
    float4 b1 = *(const float4*)(bias + tx * 4 + 64);
    float B_[8] = {b0.x, b0.y, b0.z, b0.w, b1.x, b1.y, b1.z, b1.w};
#pragma unroll
    for (int i = 0; i < 4; ++i) {
        int row = m0 + ty * 4 + i;
        if (row < M) {
            float4 u0, u1;
            float v[8];
#pragma unroll
            for (int j = 0; j < 8; ++j) {
                v[j] = acc[i][j] + B_[j];
                if (RELU) v[j] = fmaxf(v[j], 0.f);
            }
            u0 = make_float4(v[0], v[1], v[2], v[3]);
            u1 = make_float4(v[4], v[5], v[6], v[7]);
            *(float4*)(C + (size_t)row * NF + tx * 4)      = u0;
            *(float4*)(C + (size_t)row * NF + tx * 4 + 64) = u1;
        }
    }
}

// ---------------------------------------------------------------------------
// BN stats: per-column sum & sum of squares (input already ReLU'd when needed)
// ---------------------------------------------------------------------------
__global__ __launch_bounds__(TPB) void stats_kernel(
    const float* __restrict__ h, float* __restrict__ gsum,
    float* __restrict__ gsq, int M)
{
    __shared__ float ssum[TPB], ssq[TPB];
    int col  = threadIdx.x & 127;
    int half = threadIdx.x >> 7;
    float s = 0.f, q = 0.f;
    for (int n = blockIdx.x * 2 + half; n < M; n += gridDim.x * 2) {
        float v = h[(size_t)n * NF + col];
        s += v; q += v * v;
    }
    ssum[threadIdx.x] = s; ssq[threadIdx.x] = q;
    __syncthreads();
    if (threadIdx.x < 128) {
        atomAddF(&gsum[col], ssum[threadIdx.x] + ssum[threadIdx.x + 128]);
        atomAddF(&gsq[col],  ssq[threadIdx.x]  + ssq[threadIdx.x + 128]);
    }
}

// Fold BN into affine: a = gamma*rsqrt(var+eps), c = beta - mean*a
__global__ __launch_bounds__(128) void bn_finalize(
    const float* __restrict__ gsum, const float* __restrict__ gsq,
    const float* __restrict__ gamma, const float* __restrict__ beta,
    float* __restrict__ a, float* __restrict__ c, int M)
{
    int k = threadIdx.x;
    float invM = 1.0f / (float)M;
    float mean = gsum[k] * invM;
    float var  = fmaxf(gsq[k] * invM - mean * mean, 0.f);
    float s    = gamma[k] / sqrtf(var + BN_EPS_C);
    a[k] = s;
    c[k] = beta[k] - mean * s;
}

// ---------------------------------------------------------------------------
// Pooling: batch is SORTED -> run-length accumulate in registers, flush with
// one atomic per (graph-run, column) per block. 128 nodes per block.
// ---------------------------------------------------------------------------
__global__ __launch_bounds__(TPB) void pool_kernel(
    const float* __restrict__ h, const int* __restrict__ batch,
    float* __restrict__ pooled, float* __restrict__ counts, int M)
{
    int base = blockIdx.x * 128;
    int col  = threadIdx.x & 127;
    int half = threadIdx.x >> 7;
    int end  = min(base + 128, M);
    float acc = 0.f; int cnt = 0; int gcur = -1;
    for (int n = base + half; n < end; n += 2) {
        int g = batch[n];                 // wave-uniform
        if (g != gcur) {
            if (gcur >= 0) {
                atomAddF(&pooled[(size_t)gcur * NF + col], acc);
                if (col == 0) atomAddF(&counts[gcur], (float)cnt);
            }
            acc = 0.f; cnt = 0; gcur = g;
        }
        acc += h[(size_t)n * NF + col];
        cnt += 1;
    }
    if (gcur >= 0) {
        atomAddF(&pooled[(size_t)gcur * NF + col], acc);
        if (col == 0) atomAddF(&counts[gcur], (float)cnt);
    }
}

// ---------------------------------------------------------------------------
// Final: out[g, cls] = sum_k (a3[k]*pooled[g,k]/max(cnt,1) + c3[k]) * Wlin[k,cls] + blin
// (empty graph -> normalized value is 0, not c3)
// ---------------------------------------------------------------------------
__global__ __launch_bounds__(TPB) void final_kernel(
    const float* __restrict__ pooled, const float* __restrict__ counts,
    const float* __restrict__ a3, const float* __restrict__ c3,
    const float* __restrict__ Wlin, const float* __restrict__ blin,
    float* __restrict__ out, int G)
{
    int g = threadIdx.x;
    if (g >= G) return;
    float cntRaw = counts[g];
    float inv = 1.0f / fmaxf(cntRaw, 1.0f);
    float nonEmpty = cntRaw > 0.5f ? 1.0f : 0.0f;
    float acc0 = 0.f, acc1 = 0.f;
    for (int k = 0; k < NF; ++k) {
        float v = (a3[k] * pooled[(size_t)g * NF + k] * inv + c3[k]) * nonEmpty;
        acc0 += v * Wlin[k * 2 + 0];
        acc1 += v * Wlin[k * 2 + 1];
    }
    out[g * 2 + 0] = acc0 + blin[0];
    out[g * 2 + 1] = acc1 + blin[1];
}

// ---------------------------------------------------------------------------
extern "C" void kernel_launch(void* const* d_in, const int* in_sizes, int n_in,
                              void* d_out, int out_size, void* d_ws, size_t ws_size,
                              hipStream_t stream)
{
    const float* x     = (const float*)d_in[0];
    const int*   eidx  = (const int*)d_in[1];
    const int*   batch = (const int*)d_in[2];
    const float* W1r = (const float*)d_in[3],  *b1 = (const float*)d_in[4];
    const float* W1o = (const float*)d_in[5],  *g1 = (const float*)d_in[6],  *be1 = (const float*)d_in[7];
    const float* W2r = (const float*)d_in[8],  *b2 = (const float*)d_in[9];
    const float* W2o = (const float*)d_in[10], *g2 = (const float*)d_in[11], *be2 = (const float*)d_in[12];
    const float* W3r = (const float*)d_in[13], *b3 = (const float*)d_in[14];
    const float* W3o = (const float*)d_in[15], *g3 = (const float*)d_in[16], *be3 = (const float*)d_in[17];
    const float* Wlin = (const float*)d_in[18], *blin = (const float*)d_in[19];
    float* out = (float*)d_out;

    const int M = in_sizes[0] / NF;        // 100000 nodes
    const int E = in_sizes[1] / 2;         // 1.6M edges
    const int G = out_size / 2;            // 256 graphs
    const int* src = eidx;
    const int* dst = eidx + E;

    const size_t NODEF = (size_t)M * NF;   // floats per node-feature buffer

    float* bufA  = (float*)d_ws;           // 51.2 MB
    float* bufB  = bufA + NODEF;           // 51.2 MB
    float* smallz = bufB + NODEF;
    float* gsum1 = smallz;        float* gsq1 = smallz + 128;
    float* gsum2 = smallz + 256;  float* gsq2 = smallz + 384;
    float* gsum3 = smallz + 512;  float* gsq3 = smallz + 640;
    float* counts = smallz + 768;                 // 256
    float* pooled = smallz + 768 + 256;           // G*NF = 32768
    float* ac     = pooled + (size_t)G * NF;      // a1,c1,a2,c2,a3,c3
    float* a1 = ac;       float* c1 = ac + 128;
    float* a2 = ac + 256; float* c2 = ac + 384;
    float* a3 = ac + 512; float* c3 = ac + 640;

    const size_t NB = NODEF * sizeof(float);
    const int scatterBlocks = (int)(((size_t)E * 64 + TPB - 1) / TPB);
    const int gemmBlocks    = (M + 63) / 64;
    const int poolBlocks    = (M + 127) / 128;
    const int statsBlocks   = 1024;

    // zero: gsum/gsq (768) + counts (256) + pooled (32768)
    hipMemsetAsync(smallz, 0, (768 + 256 + (size_t)G * NF) * sizeof(float), stream);

    // ---- layer 1
    hipMemsetAsync(bufA, 0, NB, stream);
    scatter_kernel<false><<<scatterBlocks, TPB, 0, stream>>>(x, src, dst, nullptr, nullptr, bufA, E);
    gemm_conv<true, false><<<gemmBlocks, TPB, 0, stream>>>(bufA, x, nullptr, nullptr,
                                                           W1r, W1o, b1, bufA, M);   // r1 = bufA (in-place)
    stats_kernel<<<statsBlocks, TPB, 0, stream>>>(bufA, gsum1, gsq1, M);
    bn_finalize<<<1, 128, 0, stream>>>(gsum1, gsq1, g1, be1, a1, c1, M);

    // ---- layer 2
    hipMemsetAsync(bufB, 0, NB, stream);
    scatter_kernel<true><<<scatterBlocks, TPB, 0, stream>>>(bufA, src, dst, a1, c1, bufB, E);
    gemm_conv<true, true><<<gemmBlocks, TPB, 0, stream>>>(bufB, bufA, a1, c1,
                                                          W2r, W2o, b2, bufB, M);    // r2 = bufB (in-place)
    stats_kernel<<<statsBlocks, TPB, 0, stream>>>(bufB, gsum2, gsq2, M);
    bn_finalize<<<1, 128, 0, stream>>>(gsum2, gsq2, g2, be2, a2, c2, M);

    // ---- layer 3 (no ReLU)
    hipMemsetAsync(bufA, 0, NB, stream);
    scatter_kernel<true><<<scatterBlocks, TPB, 0, stream>>>(bufB, src, dst, a2, c2, bufA, E);
    gemm_conv<false, true><<<gemmBlocks, TPB, 0, stream>>>(bufA, bufB, a2, c2,
                                                           W3r, W3o, b3, bufA, M);   // h3 = bufA (in-place)
    stats_kernel<<<statsBlocks, TPB, 0, stream>>>(bufA, gsum3, gsq3, M);
    bn_finalize<<<1, 128, 0, stream>>>(gsum3, gsq3, g3, be3, a3, c3, M);

    // ---- pool + classify
    pool_kernel<<<poolBlocks, TPB, 0, stream>>>(bufA, batch, pooled, counts, M);
    final_kernel<<<1, TPB, 0, stream>>>(pooled, counts, a3, c3, Wlin, blin, out, G);
}

// Round 2
// 1336.137 us; speedup vs baseline: 3.6071x; 3.6071x over previous
//
#include <hip/hip_runtime.h>
#include <math.h>

#define TPB 256
#define NF 128          // feature width (all layers)
#define BN_EPS_C 1e-5f

// ---------------------------------------------------------------------------
// fast fire-and-forget f32 atomic add (hardware global_atomic_add_f32)
// ---------------------------------------------------------------------------
__device__ __forceinline__ void atomAddF(float* p, float v) {
    unsafeAtomicAdd(p, v);
}

// ===========================================================================
// CSR build: deg histogram -> exclusive scan (3 kernels) -> cursor fill
// ===========================================================================
__global__ __launch_bounds__(TPB) void hist_kernel(
    const int* __restrict__ dst, int* __restrict__ deg, int E)
{
    int e = blockIdx.x * TPB + threadIdx.x;
    if (e < E) atomicAdd(&deg[dst[e]], 1);
}

// 1024 elements per block (256 thr x 4)
__global__ __launch_bounds__(TPB) void scan_phase1(
    const int* __restrict__ deg, int* __restrict__ rowptr,
    int* __restrict__ bsums, int M)
{
    __shared__ int sd[TPB];
    int t = threadIdx.x;
    int base = blockIdx.x * 1024 + t * 4;
    int v0 = (base + 0 < M) ? deg[base + 0] : 0;
    int v1 = (base + 1 < M) ? deg[base + 1] : 0;
    int v2 = (base + 2 < M) ? deg[base + 2] : 0;
    int v3 = (base + 3 < M) ? deg[base + 3] : 0;
    int tot = v0 + v1 + v2 + v3;
    sd[t] = tot; __syncthreads();
    for (int off = 1; off < TPB; off <<= 1) {
        int x = (t >= off) ? sd[t - off] : 0;
        __syncthreads();
        sd[t] += x;
        __syncthreads();
    }
    int excl = sd[t] - tot;
    if (t == TPB - 1) bsums[blockIdx.x] = sd[TPB - 1];
    if (base + 0 < M) rowptr[base + 0] = excl;
    if (base + 1 < M) rowptr[base + 1] = excl + v0;
    if (base + 2 < M) rowptr[base + 2] = excl + v0 + v1;
    if (base + 3 < M) rowptr[base + 3] = excl + v0 + v1 + v2;
}

// single block: exclusive-scan bsums in place (general nb), set rowptr[M]=E
__global__ __launch_bounds__(TPB) void scan_phase2(
    int* __restrict__ bsums, int nb, int* __restrict__ rowptr, int M, int E)
{
    __shared__ int sd[TPB];
    int t = threadIdx.x;
    int k = (nb + TPB - 1) / TPB;
    int lo = t * k, hi = min(lo + k, nb);
    int sum = 0;
    for (int i = lo; i < hi; ++i) sum += bsums[i];
    sd[t] = sum; __syncthreads();
    for (int off = 1; off < TPB; off <<= 1) {
        int x = (t >= off) ? sd[t - off] : 0;
        __syncthreads();
        sd[t] += x;
        __syncthreads();
    }
    int run = sd[t] - sum;
    for (int i = lo; i < hi; ++i) { int v = bsums[i]; bsums[i] = run; run += v; }
    if (t == 0) rowptr[M] = E;
}

__global__ __launch_bounds__(TPB) void scan_phase3(
    int* __restrict__ rowptr, const int* __restrict__ bsums,
    int* __restrict__ cursor, int M)
{
    int i = blockIdx.x * TPB + threadIdx.x;
    if (i < M) {
        int v = rowptr[i] + bsums[i >> 10];
        rowptr[i] = v;
        cursor[i] = v;
    }
}

__global__ __launch_bounds__(TPB) void fill_csr(
    const int* __restrict__ src, const int* __restrict__ dst,
    int* __restrict__ cursor, int* __restrict__ srcs, int E)
{
    int e = blockIdx.x * TPB + threadIdx.x;
    if (e >= E) return;
    int d = dst[e];
    int pos = atomicAdd(&cursor[d], 1);
    srcs[pos] = src[e];
}

// ===========================================================================
// Gather aggregation: one wave per node, float2 per lane (128 feats).
// agg[n] = a * sum_{j in N(n)} h[j] + c * deg(n)   (BN affine distributed)
// ===========================================================================
template<bool NORM>
__global__ __launch_bounds__(TPB) void gather_agg(
    const float* __restrict__ h, const int* __restrict__ rowptr,
    const int* __restrict__ srcs,
    const float* __restrict__ na, const float* __restrict__ nc,
    float* __restrict__ agg, int M)
{
    int wid = (blockIdx.x * TPB + threadIdx.x) >> 6;
    if (wid >= M) return;
    int lane = threadIdx.x & 63;
    int start = rowptr[wid], end = rowptr[wid + 1];

    float2 a0 = make_float2(0.f, 0.f), a1 = a0, a2 = a0, a3 = a0;
    int e = start;
    for (; e + 4 <= end; e += 4) {           // 4 independent gathers in flight
        int s0 = srcs[e + 0], s1 = srcs[e + 1], s2 = srcs[e + 2], s3 = srcs[e + 3];
        float2 v0 = *(const float2*)(h + (size_t)s0 * NF + lane * 2);
        float2 v1 = *(const float2*)(h + (size_t)s1 * NF + lane * 2);
        float2 v2 = *(const float2*)(h + (size_t)s2 * NF + lane * 2);
        float2 v3 = *(const float2*)(h + (size_t)s3 * NF + lane * 2);
        a0.x += v0.x; a0.y += v0.y;
        a1.x += v1.x; a1.y += v1.y;
        a2.x += v2.x; a2.y += v2.y;
        a3.x += v3.x; a3.y += v3.y;
    }
    for (; e < end; ++e) {
        int s = srcs[e];
        float2 v = *(const float2*)(h + (size_t)s * NF + lane * 2);
        a0.x += v.x; a0.y += v.y;
    }
    float2 acc = make_float2(a0.x + a1.x + a2.x + a3.x,
                             a0.y + a1.y + a2.y + a3.y);
    float2 res;
    if (NORM) {
        float degf = (float)(end - start);
        float2 aa = *(const float2*)(na + lane * 2);
        float2 cc = *(const float2*)(nc + lane * 2);
        res.x = acc.x * aa.x + cc.x * degf;
        res.y = acc.y * aa.y + cc.y * degf;
    } else {
        res = acc;
    }
    *(float2*)(agg + (size_t)wid * NF + lane * 2) = res;
}

// ===========================================================================
// Dual-A GEMM: C = Aagg @ Wr + norm(Ax) @ Wroot + bias, optional ReLU,
// optional fused BN column stats (sum / sumsq via LDS reduce + 2 atomics/col).
// Tile: 64 rows x 128 cols, K chunked by 16. 256 thr, 4x8 per thread.
// C may alias Aagg (in-place): each block writes only rows it fully consumed.
// ===========================================================================
template<bool RELU, bool NORM, bool STATS>
__global__ __launch_bounds__(TPB) void gemm_conv(
    const float* Aagg, const float* Ax,                    // may alias C
    const float* __restrict__ na, const float* __restrict__ nc,
    const float* __restrict__ Wr, const float* __restrict__ Wroot,
    const float* __restrict__ bias, float* C,
    float* __restrict__ gsum, float* __restrict__ gsq, int M)
{
    __shared__ __align__(16) float sAa[16][68];
    __shared__ __align__(16) float sAx[16][68];
    __shared__ __align__(16) float sWr[16][NF];   // reused as stats scratch
    __shared__ __align__(16) float sWo[16][NF];   // reused as stats scratch

    const int tid = threadIdx.x;
    const int tx  = tid & 15;
    const int ty  = tid >> 4;
    const int m0  = blockIdx.x * 64;

    float acc[4][8];
#pragma unroll
    for (int i = 0; i < 4; ++i)
#pragma unroll
        for (int j = 0; j < 8; ++j) acc[i][j] = 0.f;

    const int lr = tid >> 2;
    const int lk = (tid & 3) * 4;
    const int wrow = tid >> 4;
    const int wcol = (tid & 15) * 8;

    for (int kc = 0; kc < NF; kc += 16) {
        int row = m0 + lr;
        float4 va = make_float4(0.f, 0.f, 0.f, 0.f);
        float4 vx = va;
        if (row < M) {
            va = *(const float4*)(Aagg + (size_t)row * NF + kc + lk);
            vx = *(const float4*)(Ax   + (size_t)row * NF + kc + lk);
        }
        if (NORM) {
            float4 a4 = *(const float4*)(na + kc + lk);
            float4 c4 = *(const float4*)(nc + kc + lk);
            vx.x = vx.x * a4.x + c4.x;  vx.y = vx.y * a4.y + c4.y;
            vx.z = vx.z * a4.z + c4.z;  vx.w = vx.w * a4.w + c4.w;
        }
        float4 w0 = *(const float4*)(Wr    + (size_t)(kc + wrow) * NF + wcol);
        float4 w1 = *(const float4*)(Wr    + (size_t)(kc + wrow) * NF + wcol + 4);
        float4 o0 = *(const float4*)(Wroot + (size_t)(kc + wrow) * NF + wcol);
        float4 o1 = *(const float4*)(Wroot + (size_t)(kc + wrow) * NF + wcol + 4);

        __syncthreads();
        sAa[lk + 0][lr] = va.x; sAa[lk + 1][lr] = va.y;
        sAa[lk + 2][lr] = va.z; sAa[lk + 3][lr] = va.w;
        sAx[lk + 0][lr] = vx.x; sAx[lk + 1][lr] = vx.y;
        sAx[lk + 2][lr] = vx.z; sAx[lk + 3][lr] = vx.w;
        *(float4*)&sWr[wrow][wcol]     = w0;
        *(float4*)&sWr[wrow][wcol + 4] = w1;
        *(float4*)&sWo[wrow][wcol]     = o0;
        *(float4*)&sWo[wrow][wcol + 4] = o1;
        __syncthreads();

#pragma unroll
        for (int kk = 0; kk < 16; ++kk) {
            float4 aa = *(const float4*)&sAa[kk][ty * 4];
            float4 ax = *(const float4*)&sAx[kk][ty * 4];
            float4 r0 = *(const float4*)&sWr[kk][tx * 4];
            float4 r1 = *(const float4*)&sWr[kk][tx * 4 + 64];
            float4 q0 = *(const float4*)&sWo[kk][tx * 4];
            float4 q1 = *(const float4*)&sWo[kk][tx * 4 + 64];
            float A_[4] = {aa.x, aa.y, aa.z, aa.w};
            float X_[4] = {ax.x, ax.y, ax.z, ax.w};
            float R_[8] = {r0.x, r0.y, r0.z, r0.w, r1.x, r1.y, r1.z, r1.w};
            float Q_[8] = {q0.x, q0.y, q0.z, q0.w, q1.x, q1.y, q1.z, q1.w};
#pragma unroll
            for (int i = 0; i < 4; ++i)
#pragma unroll
                for (int j = 0; j < 8; ++j)
                    acc[i][j] += A_[i] * R_[j] + X_[i] * Q_[j];
        }
    }

    // ---- epilogue: bias (+ReLU), coalesced float4 stores, fused stats
    float4 b0 = *(const float4*)(bias + tx * 4);
    float4 b1 = *(const float4*)(bias + tx * 4 + 64);
    float B_[8] = {b0.x, b0.y, b0.z, b0.w, b1.x, b1.y, b1.z, b1.w};
    float s8[8], q8[8];
#pragma unroll
    for (int j = 0; j < 8; ++j) { s8[j] = 0.f; q8[j] = 0.f; }

#pragma unroll
    for (int i = 0; i < 4; ++i) {
        int row = m0 + ty * 4 + i;
        if (row < M) {
            float v[8];
#pragma unroll
            for (int j = 0; j < 8; ++j) {
                v[j] = acc[i][j] + B_[j];
                if (RELU) v[j] = fmaxf(v[j], 0.f);
                if (STATS) { s8[j] += v[j]; q8[j] += v[j] * v[j]; }
            }
            *(float4*)(C + (size_t)row * NF + tx * 4)      = make_float4(v[0], v[1], v[2], v[3]);
            *(float4*)(C + (size_t)row * NF + tx * 4 + 64) = make_float4(v[4], v[5], v[6], v[7]);
        }
    }

    if (STATS) {
        __syncthreads();                       // done reading sWr/sWo
        float* ss = &sWr[0][0];                // [16][128] partials
        float* sq = &sWo[0][0];
#pragma unroll
        for (int j = 0; j < 8; ++j) {
            int col = tx * 4 + ((j < 4) ? j : (60 + j));   // j>=4 -> 64 + tx*4 + (j-4)
            ss[ty * NF + col] = s8[j];
            sq[ty * NF + col] = q8[j];
        }
        __syncthreads();
        if (tid < NF) {
            float s = 0.f, q = 0.f;
#pragma unroll
            for (int g = 0; g < 16; ++g) {
                s += ss[g * NF + tid];
                q += sq[g * NF + tid];
            }
            atomAddF(&gsum[tid], s);
            atomAddF(&gsq[tid], q);
        }
    }
}

// Fold BN into affine: a = gamma*rsqrt(var+eps), c = beta - mean*a
__global__ __launch_bounds__(128) void bn_finalize(
    const float* __restrict__ gsum, const float* __restrict__ gsq,
    const float* __restrict__ gamma, const float* __restrict__ beta,
    float* __restrict__ a, float* __restrict__ c, int M)
{
    int k = threadIdx.x;
    float invM = 1.0f / (float)M;
    float mean = gsum[k] * invM;
    float var  = fmaxf(gsq[k] * invM - mean * mean, 0.f);
    float s    = gamma[k] / sqrtf(var + BN_EPS_C);
    a[k] = s;
    c[k] = beta[k] - mean * s;
}

// ---------------------------------------------------------------------------
// Pooling: batch is SORTED -> run-length accumulate, flush per run per block.
// ---------------------------------------------------------------------------
__global__ __launch_bounds__(TPB) void pool_kernel(
    const float* __restrict__ h, const int* __restrict__ batch,
    float* __restrict__ pooled, float* __restrict__ counts, int M)
{
    int base = blockIdx.x * 128;
    int col  = threadIdx.x & 127;
    int half = threadIdx.x >> 7;
    int end  = min(base + 128, M);
    float acc = 0.f; int cnt = 0; int gcur = -1;
    for (int n = base + half; n < end; n += 2) {
        int g = batch[n];
        if (g != gcur) {
            if (gcur >= 0) {
                atomAddF(&pooled[(size_t)gcur * NF + col], acc);
                if (col == 0) atomAddF(&counts[gcur], (float)cnt);
            }
            acc = 0.f; cnt = 0; gcur = g;
        }
        acc += h[(size_t)n * NF + col];
        cnt += 1;
    }
    if (gcur >= 0) {
        atomAddF(&pooled[(size_t)gcur * NF + col], acc);
        if (col == 0) atomAddF(&counts[gcur], (float)cnt);
    }
}

__global__ __launch_bounds__(TPB) void final_kernel(
    const float* __restrict__ pooled, const float* __restrict__ counts,
    const float* __restrict__ a3, const float* __restrict__ c3,
    const float* __restrict__ Wlin, const float* __restrict__ blin,
    float* __restrict__ out, int G)
{
    int g = threadIdx.x;
    if (g >= G) return;
    float cntRaw = counts[g];
    float inv = 1.0f / fmaxf(cntRaw, 1.0f);
    float nonEmpty = cntRaw > 0.5f ? 1.0f : 0.0f;
    float acc0 = 0.f, acc1 = 0.f;
    for (int k = 0; k < NF; ++k) {
        float v = (a3[k] * pooled[(size_t)g * NF + k] * inv + c3[k]) * nonEmpty;
        acc0 += v * Wlin[k * 2 + 0];
        acc1 += v * Wlin[k * 2 + 1];
    }
    out[g * 2 + 0] = acc0 + blin[0];
    out[g * 2 + 1] = acc1 + blin[1];
}

// ---------------------------------------------------------------------------
extern "C" void kernel_launch(void* const* d_in, const int* in_sizes, int n_in,
                              void* d_out, int out_size, void* d_ws, size_t ws_size,
                              hipStream_t stream)
{
    const float* x     = (const float*)d_in[0];
    const int*   eidx  = (const int*)d_in[1];
    const int*   batch = (const int*)d_in[2];
    const float* W1r = (const float*)d_in[3],  *b1 = (const float*)d_in[4];
    const float* W1o = (const float*)d_in[5],  *g1 = (const float*)d_in[6],  *be1 = (const float*)d_in[7];
    const float* W2r = (const float*)d_in[8],  *b2 = (const float*)d_in[9];
    const float* W2o = (const float*)d_in[10], *g2 = (const float*)d_in[11], *be2 = (const float*)d_in[12];
    const float* W3r = (const float*)d_in[13], *b3 = (const float*)d_in[14];
    const float* W3o = (const float*)d_in[15], *g3 = (const float*)d_in[16], *be3 = (const float*)d_in[17];
    const float* Wlin = (const float*)d_in[18], *blin = (const float*)d_in[19];
    float* out = (float*)d_out;

    const int M = in_sizes[0] / NF;        // 100000 nodes
    const int E = in_sizes[1] / 2;         // 1.6M edges
    const int G = out_size / 2;            // 256 graphs
    const int* src = eidx;
    const int* dst = eidx + E;

    const size_t NODEF = (size_t)M * NF;

    // ---- workspace layout (floats first for 16B-aligned float4 access) ----
    float* bufA  = (float*)d_ws;                   // NODEF
    float* bufB  = bufA + NODEF;                   // NODEF
    float* smallz = bufB + NODEF;
    float* gsum1 = smallz;        float* gsq1 = smallz + 128;
    float* gsum2 = smallz + 256;  float* gsq2 = smallz + 384;
    float* gsum3 = smallz + 512;  float* gsq3 = smallz + 640;
    float* counts = smallz + 768;                  // G
    float* pooled = smallz + 768 + 256;            // G*NF
    float* ac     = pooled + (size_t)G * NF;
    float* a1 = ac;       float* c1 = ac + 128;
    float* a2 = ac + 256; float* c2 = ac + 384;
    float* a3 = ac + 512; float* c3 = ac + 640;
    int* ints   = (int*)(ac + 768);
    int* rowptr = ints;                            // M+1
    int* cursor = rowptr + (M + 1);                // M
    int* deg    = cursor + M;                      // M
    int* srcs   = deg + M;                         // E

    const int scanBlocks = (M + 1023) / 1024;
    const int gridE      = (E + TPB - 1) / TPB;
    const int gridM      = (M + TPB - 1) / TPB;
    const int gatherBlocks = (M * 64 + TPB - 1) / TPB;   // 1 wave / node
    const int gemmBlocks   = (M + 63) / 64;
    const int poolBlocks   = (M + 127) / 128;

    // zero: gsum/gsq (768) + counts (256) + pooled (G*NF); deg histogram
    hipMemsetAsync(smallz, 0, (768 + 256 + (size_t)G * NF) * sizeof(float), stream);
    hipMemsetAsync(deg, 0, (size_t)M * sizeof(int), stream);

    // ---- build reverse CSR (dst-grouped), reused by all 3 layers ----
    hist_kernel <<<gridE, TPB, 0, stream>>>(dst, deg, E);
    scan_phase1 <<<scanBlocks, TPB, 0, stream>>>(deg, rowptr, cursor /*tmp bsums*/, M);
    scan_phase2 <<<1, TPB, 0, stream>>>(cursor, scanBlocks, rowptr, M, E);
    scan_phase3 <<<gridM, TPB, 0, stream>>>(rowptr, cursor, deg /*cursor out*/, M);
    // note: after phase3, 'deg' holds the fill cursors (deg data no longer needed)
    fill_csr    <<<gridE, TPB, 0, stream>>>(src, dst, deg, srcs, E);

    // ---- layer 1
    gather_agg<false><<<gatherBlocks, TPB, 0, stream>>>(x, rowptr, srcs, nullptr, nullptr, bufA, M);
    gemm_conv<true, false, true><<<gemmBlocks, TPB, 0, stream>>>(
        bufA, x, nullptr, nullptr, W1r, W1o, b1, bufA, gsum1, gsq1, M);
    bn_finalize<<<1, 128, 0, stream>>>(gsum1, gsq1, g1, be1, a1, c1, M);

    // ---- layer 2
    gather_agg<true><<<gatherBlocks, TPB, 0, stream>>>(bufA, rowptr, srcs, a1, c1, bufB, M);
    gemm_conv<true, true, true><<<gemmBlocks, TPB, 0, stream>>>(
        bufB, bufA, a1, c1, W2r, W2o, b2, bufB, gsum2, gsq2, M);
    bn_finalize<<<1, 128, 0, stream>>>(gsum2, gsq2, g2, be2, a2, c2, M);

    // ---- layer 3 (no ReLU)
    gather_agg<true><<<gatherBlocks, TPB, 0, stream>>>(bufB, rowptr, srcs, a2, c2, bufA, M);
    gemm_conv<false, true, true><<<gemmBlocks, TPB, 0, stream>>>(
        bufA, bufB, a2, c2, W3r, W3o, b3, bufA, gsum3, gsq3, M);
    bn_finalize<<<1, 128, 0, stream>>>(gsum3, gsq3, g3, be3, a3, c3, M);

    // ---- pool + classify
    pool_kernel<<<poolBlocks, TPB, 0, stream>>>(bufA, batch, pooled, counts, M);
    final_kernel<<<1, TPB, 0, stream>>>(pooled, counts, a3, c3, Wlin, blin, out, G);
}

// Round 3
// 1035.797 us; speedup vs baseline: 4.6530x; 1.2900x over previous
//
#include <hip/hip_runtime.h>
#include <math.h>
#include <stdint.h>

#define TPB 256
#define NF 128          // feature width (all layers)
#define BN_EPS_C 1e-5f

typedef __attribute__((ext_vector_type(8))) short bf16x8;   // 8 bf16 (4 VGPRs)
typedef __attribute__((ext_vector_type(4))) float f32x4;    // 4 fp32

// ---------------------------------------------------------------------------
__device__ __forceinline__ void atomAddF(float* p, float v) {
    unsafeAtomicAdd(p, v);
}

// fp32 <-> bf16 (RNE), bit-level to avoid header type friction
__device__ __forceinline__ short f2bf(float f) {
    unsigned u = __float_as_uint(f);
    unsigned r = (u + 0x7FFFu + ((u >> 16) & 1u)) >> 16;
    return (short)r;
}
__device__ __forceinline__ float bf2f(short b) {
    return __uint_as_float(((unsigned)(unsigned short)b) << 16);
}

// ===========================================================================
// CSR build: deg histogram -> exclusive scan (3 kernels) -> cursor fill
// ===========================================================================
__global__ __launch_bounds__(TPB) void hist_kernel(
    const int* __restrict__ dst, int* __restrict__ deg, int E)
{
    int e = blockIdx.x * TPB + threadIdx.x;
    if (e < E) atomicAdd(&deg[dst[e]], 1);
}

__global__ __launch_bounds__(TPB) void scan_phase1(
    const int* __restrict__ deg, int* __restrict__ rowptr,
    int* __restrict__ bsums, int M)
{
    __shared__ int sd[TPB];
    int t = threadIdx.x;
    int base = blockIdx.x * 1024 + t * 4;
    int v0 = (base + 0 < M) ? deg[base + 0] : 0;
    int v1 = (base + 1 < M) ? deg[base + 1] : 0;
    int v2 = (base + 2 < M) ? deg[base + 2] : 0;
    int v3 = (base + 3 < M) ? deg[base + 3] : 0;
    int tot = v0 + v1 + v2 + v3;
    sd[t] = tot; __syncthreads();
    for (int off = 1; off < TPB; off <<= 1) {
        int x = (t >= off) ? sd[t - off] : 0;
        __syncthreads();
        sd[t] += x;
        __syncthreads();
    }
    int excl = sd[t] - tot;
    if (t == TPB - 1) bsums[blockIdx.x] = sd[TPB - 1];
    if (base + 0 < M) rowptr[base + 0] = excl;
    if (base + 1 < M) rowptr[base + 1] = excl + v0;
    if (base + 2 < M) rowptr[base + 2] = excl + v0 + v1;
    if (base + 3 < M) rowptr[base + 3] = excl + v0 + v1 + v2;
}

__global__ __launch_bounds__(TPB) void scan_phase2(
    int* __restrict__ bsums, int nb, int* __restrict__ rowptr, int M, int E)
{
    __shared__ int sd[TPB];
    int t = threadIdx.x;
    int k = (nb + TPB - 1) / TPB;
    int lo = t * k, hi = min(lo + k, nb);
    int sum = 0;
    for (int i = lo; i < hi; ++i) sum += bsums[i];
    sd[t] = sum; __syncthreads();
    for (int off = 1; off < TPB; off <<= 1) {
        int x = (t >= off) ? sd[t - off] : 0;
        __syncthreads();
        sd[t] += x;
        __syncthreads();
    }
    int run = sd[t] - sum;
    for (int i = lo; i < hi; ++i) { int v = bsums[i]; bsums[i] = run; run += v; }
    if (t == 0) rowptr[M] = E;
}

__global__ __launch_bounds__(TPB) void scan_phase3(
    int* __restrict__ rowptr, const int* __restrict__ bsums,
    int* __restrict__ cursor, int M)
{
    int i = blockIdx.x * TPB + threadIdx.x;
    if (i < M) {
        int v = rowptr[i] + bsums[i >> 10];
        rowptr[i] = v;
        cursor[i] = v;
    }
}

__global__ __launch_bounds__(TPB) void fill_csr(
    const int* __restrict__ src, const int* __restrict__ dst,
    int* __restrict__ cursor, int* __restrict__ srcs, int E)
{
    int e = blockIdx.x * TPB + threadIdx.x;
    if (e >= E) return;
    int d = dst[e];
    int pos = atomicAdd(&cursor[d], 1);
    srcs[pos] = src[e];
}

// ===========================================================================
// Gather aggregation: one wave per node, float2 per lane (128 feats).
// agg[n] = a * sum_{j in N(n)} h[j] + c * deg(n)   (BN affine distributed)
// ===========================================================================
template<bool NORM>
__global__ __launch_bounds__(TPB) void gather_agg(
    const float* __restrict__ h, const int* __restrict__ rowptr,
    const int* __restrict__ srcs,
    const float* __restrict__ na, const float* __restrict__ nc,
    float* __restrict__ agg, int M)
{
    int wid = (blockIdx.x * TPB + threadIdx.x) >> 6;
    if (wid >= M) return;
    int lane = threadIdx.x & 63;
    int start = rowptr[wid], end = rowptr[wid + 1];

    float2 a0 = make_float2(0.f, 0.f), a1 = a0, a2 = a0, a3 = a0;
    int e = start;
    for (; e + 4 <= end; e += 4) {
        int s0 = srcs[e + 0], s1 = srcs[e + 1], s2 = srcs[e + 2], s3 = srcs[e + 3];
        float2 v0 = *(const float2*)(h + (size_t)s0 * NF + lane * 2);
        float2 v1 = *(const float2*)(h + (size_t)s1 * NF + lane * 2);
        float2 v2 = *(const float2*)(h + (size_t)s2 * NF + lane * 2);
        float2 v3 = *(const float2*)(h + (size_t)s3 * NF + lane * 2);
        a0.x += v0.x; a0.y += v0.y;
        a1.x += v1.x; a1.y += v1.y;
        a2.x += v2.x; a2.y += v2.y;
        a3.x += v3.x; a3.y += v3.y;
    }
    for (; e < end; ++e) {
        int s = srcs[e];
        float2 v = *(const float2*)(h + (size_t)s * NF + lane * 2);
        a0.x += v.x; a0.y += v.y;
    }
    float2 acc = make_float2(a0.x + a1.x + a2.x + a3.x,
                             a0.y + a1.y + a2.y + a3.y);
    float2 res;
    if (NORM) {
        float degf = (float)(end - start);
        float2 aa = *(const float2*)(na + lane * 2);
        float2 cc = *(const float2*)(nc + lane * 2);
        res.x = acc.x * aa.x + cc.x * degf;
        res.y = acc.y * aa.y + cc.y * degf;
    } else {
        res = acc;
    }
    *(float2*)(agg + (size_t)wid * NF + lane * 2) = res;
}

// ===========================================================================
// W prep: transpose + concat + split into bf16 hi/lo.
// Wt[n][k], k in [0,256): k<128 -> Wr[k][n], else Wroot[k-128][n]
// ===========================================================================
__global__ __launch_bounds__(256) void wsplit_kernel(
    const float* __restrict__ Wr, const float* __restrict__ Wo,
    short* __restrict__ hi, short* __restrict__ lo)
{
    int n = blockIdx.x;      // 0..127
    int k = threadIdx.x;     // 0..255
    float v = (k < NF) ? Wr[k * NF + n] : Wo[(k - NF) * NF + n];
    short h = f2bf(v);
    hi[n * 256 + k] = h;
    lo[n * 256 + k] = f2bf(v - bf2f(h));
}

// ===========================================================================
// MFMA dual GEMM via split-bf16 (Markidis 3-term):
//   C = [Aagg | norm(Ax)] @ Wt^T + bias  (+ReLU, +fused BN column stats)
// mfma_f32_16x16x32_bf16, verified layouts (m89/m91):
//   A[m=lane&15][k=(lane>>4)*8+j], B^T[n=lane&15][k=(lane>>4)*8+j],
//   C: col=lane&15, row=(lane>>4)*4+reg.
// Block = 256 thr = 4 waves; wave owns 32 rows x 128 cols (2x8 16x16 tiles).
// No LDS staging: A frags direct from global fp32 (64B-coalesced), W frags
// direct from the 128KB L1/L2-resident split-W. C may alias Aagg (epilogue
// writes only rows this block fully consumed).
// ===========================================================================
template<bool RELU, bool NORM>
__global__ __launch_bounds__(TPB, 2) void gemm_mfma(
    const float* Aagg, const float* Ax,                    // may alias C
    const float* __restrict__ na, const float* __restrict__ nc,
    const short* __restrict__ wt_hi, const short* __restrict__ wt_lo,
    const float* __restrict__ bias, float* C,
    float* __restrict__ gsum, float* __restrict__ gsq, int M)
{
    __shared__ float ssum[16][NF];
    __shared__ float ssq [16][NF];

    const int tid  = threadIdx.x;
    const int wid  = tid >> 6;
    const int lane = tid & 63;
    const int lg   = lane >> 4;        // quad 0..3
    const int ln   = lane & 15;
    const int rowbase = blockIdx.x * 128 + wid * 32;

    f32x4 acc[2][8];
#pragma unroll
    for (int i = 0; i < 2; ++i)
#pragma unroll
        for (int j = 0; j < 8; ++j) acc[i][j] = (f32x4){0.f, 0.f, 0.f, 0.f};

#pragma unroll
    for (int kc = 0; kc < 8; ++kc) {
        const int k0 = kc * 32;                     // concat-K chunk base
        const bool second = (k0 >= NF);
        const int kcol = (second ? k0 - NF : k0) + lg * 8;
        const float* Asrc = second ? Ax : Aagg;

        bf16x8 ahi[2], alo[2];
#pragma unroll
        for (int mt = 0; mt < 2; ++mt) {
            int row = rowbase + mt * 16 + ln;
            f32x4 v0 = (f32x4){0.f, 0.f, 0.f, 0.f};
            f32x4 v1 = v0;
            if (row < M) {
                v0 = *(const f32x4*)(Asrc + (size_t)row * NF + kcol);
                v1 = *(const f32x4*)(Asrc + (size_t)row * NF + kcol + 4);
            }
            if (NORM && second) {
                f32x4 a0 = *(const f32x4*)(na + kcol);
                f32x4 a1 = *(const f32x4*)(na + kcol + 4);
                f32x4 c0 = *(const f32x4*)(nc + kcol);
                f32x4 c1 = *(const f32x4*)(nc + kcol + 4);
                v0 = v0 * a0 + c0;
                v1 = v1 * a1 + c1;
            }
            float vv[8] = {v0.x, v0.y, v0.z, v0.w, v1.x, v1.y, v1.z, v1.w};
#pragma unroll
            for (int j = 0; j < 8; ++j) {
                short h = f2bf(vv[j]);
                ahi[mt][j] = h;
                alo[mt][j] = f2bf(vv[j] - bf2f(h));
            }
        }

#pragma unroll
        for (int nt = 0; nt < 8; ++nt) {
            const size_t wof = (size_t)(nt * 16 + ln) * 256 + k0 + lg * 8;
            bf16x8 bhi = *(const bf16x8*)(wt_hi + wof);
            bf16x8 blo = *(const bf16x8*)(wt_lo + wof);
#pragma unroll
            for (int mt = 0; mt < 2; ++mt) {
                acc[mt][nt] = __builtin_amdgcn_mfma_f32_16x16x32_bf16(ahi[mt], bhi, acc[mt][nt], 0, 0, 0);
                acc[mt][nt] = __builtin_amdgcn_mfma_f32_16x16x32_bf16(alo[mt], bhi, acc[mt][nt], 0, 0, 0);
                acc[mt][nt] = __builtin_amdgcn_mfma_f32_16x16x32_bf16(ahi[mt], blo, acc[mt][nt], 0, 0, 0);
            }
        }
    }

    // ---- epilogue: bias (+ReLU), store, fused BN stats ----
    float s8[8], q8[8];
#pragma unroll
    for (int nt = 0; nt < 8; ++nt) { s8[nt] = 0.f; q8[nt] = 0.f; }

#pragma unroll
    for (int nt = 0; nt < 8; ++nt) {
        int col = nt * 16 + ln;
        float b = bias[col];
#pragma unroll
        for (int mt = 0; mt < 2; ++mt) {
            int rm = rowbase + mt * 16 + lg * 4;
#pragma unroll
            for (int r = 0; r < 4; ++r) {
                int row = rm + r;
                if (row < M) {
                    float v = acc[mt][nt][r] + b;
                    if (RELU) v = fmaxf(v, 0.f);
                    C[(size_t)row * NF + col] = v;
                    s8[nt] += v;
                    q8[nt] += v * v;
                }
            }
        }
    }

    const int rg = wid * 4 + lg;       // 16 reduction rows, each covers all 128 cols
#pragma unroll
    for (int nt = 0; nt < 8; ++nt) {
        ssum[rg][nt * 16 + ln] = s8[nt];
        ssq [rg][nt * 16 + ln] = q8[nt];
    }
    __syncthreads();
    if (tid < NF) {
        float s = 0.f, q = 0.f;
#pragma unroll
        for (int g = 0; g < 16; ++g) { s += ssum[g][tid]; q += ssq[g][tid]; }
        atomAddF(&gsum[tid], s);
        atomAddF(&gsq[tid], q);
    }
}

// Fold BN into affine: a = gamma*rsqrt(var+eps), c = beta - mean*a
__global__ __launch_bounds__(128) void bn_finalize(
    const float* __restrict__ gsum, const float* __restrict__ gsq,
    const float* __restrict__ gamma, const float* __restrict__ beta,
    float* __restrict__ a, float* __restrict__ c, int M)
{
    int k = threadIdx.x;
    float invM = 1.0f / (float)M;
    float mean = gsum[k] * invM;
    float var  = fmaxf(gsq[k] * invM - mean * mean, 0.f);
    float s    = gamma[k] / sqrtf(var + BN_EPS_C);
    a[k] = s;
    c[k] = beta[k] - mean * s;
}

// ---------------------------------------------------------------------------
// Pooling: batch is SORTED -> run-length accumulate, flush per run per block.
// ---------------------------------------------------------------------------
__global__ __launch_bounds__(TPB) void pool_kernel(
    const float* __restrict__ h, const int* __restrict__ batch,
    float* __restrict__ pooled, float* __restrict__ counts, int M)
{
    int base = blockIdx.x * 128;
    int col  = threadIdx.x & 127;
    int half = threadIdx.x >> 7;
    int end  = min(base + 128, M);
    float acc = 0.f; int cnt = 0; int gcur = -1;
    for (int n = base + half; n < end; n += 2) {
        int g = batch[n];
        if (g != gcur) {
            if (gcur >= 0) {
                atomAddF(&pooled[(size_t)gcur * NF + col], acc);
                if (col == 0) atomAddF(&counts[gcur], (float)cnt);
            }
            acc = 0.f; cnt = 0; gcur = g;
        }
        acc += h[(size_t)n * NF + col];
        cnt += 1;
    }
    if (gcur >= 0) {
        atomAddF(&pooled[(size_t)gcur * NF + col], acc);
        if (col == 0) atomAddF(&counts[gcur], (float)cnt);
    }
}

__global__ __launch_bounds__(TPB) void final_kernel(
    const float* __restrict__ pooled, const float* __restrict__ counts,
    const float* __restrict__ a3, const float* __restrict__ c3,
    const float* __restrict__ Wlin, const float* __restrict__ blin,
    float* __restrict__ out, int G)
{
    int g = threadIdx.x;
    if (g >= G) return;
    float cntRaw = counts[g];
    float inv = 1.0f / fmaxf(cntRaw, 1.0f);
    float nonEmpty = cntRaw > 0.5f ? 1.0f : 0.0f;
    float acc0 = 0.f, acc1 = 0.f;
    for (int k = 0; k < NF; ++k) {
        float v = (a3[k] * pooled[(size_t)g * NF + k] * inv + c3[k]) * nonEmpty;
        acc0 += v * Wlin[k * 2 + 0];
        acc1 += v * Wlin[k * 2 + 1];
    }
    out[g * 2 + 0] = acc0 + blin[0];
    out[g * 2 + 1] = acc1 + blin[1];
}

// ---------------------------------------------------------------------------
extern "C" void kernel_launch(void* const* d_in, const int* in_sizes, int n_in,
                              void* d_out, int out_size, void* d_ws, size_t ws_size,
                              hipStream_t stream)
{
    const float* x     = (const float*)d_in[0];
    const int*   eidx  = (const int*)d_in[1];
    const int*   batch = (const int*)d_in[2];
    const float* W1r = (const float*)d_in[3],  *b1 = (const float*)d_in[4];
    const float* W1o = (const float*)d_in[5],  *g1 = (const float*)d_in[6],  *be1 = (const float*)d_in[7];
    const float* W2r = (const float*)d_in[8],  *b2 = (const float*)d_in[9];
    const float* W2o = (const float*)d_in[10], *g2 = (const float*)d_in[11], *be2 = (const float*)d_in[12];
    const float* W3r = (const float*)d_in[13], *b3 = (const float*)d_in[14];
    const float* W3o = (const float*)d_in[15], *g3 = (const float*)d_in[16], *be3 = (const float*)d_in[17];
    const float* Wlin = (const float*)d_in[18], *blin = (const float*)d_in[19];
    float* out = (float*)d_out;

    const int M = in_sizes[0] / NF;        // 100000 nodes
    const int E = in_sizes[1] / 2;         // 1.6M edges
    const int G = out_size / 2;            // 256 graphs
    const int* src = eidx;
    const int* dst = eidx + E;

    const size_t NODEF = (size_t)M * NF;

    // ---- workspace layout (floats first for 16B-aligned float4 access) ----
    float* bufA  = (float*)d_ws;                   // NODEF
    float* bufB  = bufA + NODEF;                   // NODEF
    float* smallz = bufB + NODEF;
    float* gsum1 = smallz;        float* gsq1 = smallz + 128;
    float* gsum2 = smallz + 256;  float* gsq2 = smallz + 384;
    float* gsum3 = smallz + 512;  float* gsq3 = smallz + 640;
    float* counts = smallz + 768;                  // G
    float* pooled = smallz + 768 + 256;            // G*NF
    float* ac     = pooled + (size_t)G * NF;
    float* a1 = ac;       float* c1 = ac + 128;
    float* a2 = ac + 256; float* c2 = ac + 384;
    float* a3 = ac + 512; float* c3 = ac + 640;
    int* ints   = (int*)(ac + 768);
    int* rowptr = ints;                            // M+1
    int* cursor = rowptr + (M + 1);                // M
    int* deg    = cursor + M;                      // M
    int* srcs   = deg + M;                         // E
    // split-W scratch (reused by all 3 layers; launches are sequential)
    short* wtbuf = (short*)(((uintptr_t)(srcs + E) + 15) & ~(uintptr_t)15);
    short* wt_hi = wtbuf;                          // 128*256 bf16
    short* wt_lo = wtbuf + 128 * 256;              // 128*256 bf16

    const int scanBlocks = (M + 1023) / 1024;
    const int gridE      = (E + TPB - 1) / TPB;
    const int gridM      = (M + TPB - 1) / TPB;
    const int gatherBlocks = (M * 64 + TPB - 1) / TPB;   // 1 wave / node
    const int gemmBlocks   = (M + 127) / 128;
    const int poolBlocks   = (M + 127) / 128;

    // zero: gsum/gsq (768) + counts (256) + pooled (G*NF); deg histogram
    hipMemsetAsync(smallz, 0, (768 + 256 + (size_t)G * NF) * sizeof(float), stream);
    hipMemsetAsync(deg, 0, (size_t)M * sizeof(int), stream);

    // ---- build reverse CSR (dst-grouped), reused by all 3 layers ----
    hist_kernel <<<gridE, TPB, 0, stream>>>(dst, deg, E);
    scan_phase1 <<<scanBlocks, TPB, 0, stream>>>(deg, rowptr, cursor /*tmp bsums*/, M);
    scan_phase2 <<<1, TPB, 0, stream>>>(cursor, scanBlocks, rowptr, M, E);
    scan_phase3 <<<gridM, TPB, 0, stream>>>(rowptr, cursor, deg /*cursor out*/, M);
    fill_csr    <<<gridE, TPB, 0, stream>>>(src, dst, deg, srcs, E);

    // ---- layer 1
    gather_agg<false><<<gatherBlocks, TPB, 0, stream>>>(x, rowptr, srcs, nullptr, nullptr, bufA, M);
    wsplit_kernel<<<128, 256, 0, stream>>>(W1r, W1o, wt_hi, wt_lo);
    gemm_mfma<true, false><<<gemmBlocks, TPB, 0, stream>>>(
        bufA, x, nullptr, nullptr, wt_hi, wt_lo, b1, bufA, gsum1, gsq1, M);
    bn_finalize<<<1, 128, 0, stream>>>(gsum1, gsq1, g1, be1, a1, c1, M);

    // ---- layer 2
    gather_agg<true><<<gatherBlocks, TPB, 0, stream>>>(bufA, rowptr, srcs, a1, c1, bufB, M);
    wsplit_kernel<<<128, 256, 0, stream>>>(W2r, W2o, wt_hi, wt_lo);
    gemm_mfma<true, true><<<gemmBlocks, TPB, 0, stream>>>(
        bufB, bufA, a1, c1, wt_hi, wt_lo, b2, bufB, gsum2, gsq2, M);
    bn_finalize<<<1, 128, 0, stream>>>(gsum2, gsq2, g2, be2, a2, c2, M);

    // ---- layer 3 (no ReLU)
    gather_agg<true><<<gatherBlocks, TPB, 0, stream>>>(bufB, rowptr, srcs, a2, c2, bufA, M);
    wsplit_kernel<<<128, 256, 0, stream>>>(W3r, W3o, wt_hi, wt_lo);
    gemm_mfma<false, true><<<gemmBlocks, TPB, 0, stream>>>(
        bufA, bufB, a2, c2, wt_hi, wt_lo, b3, bufA, gsum3, gsq3, M);
    bn_finalize<<<1, 128, 0, stream>>>(gsum3, gsq3, g3, be3, a3, c3, M);

    // ---- pool + classify
    pool_kernel<<<poolBlocks, TPB, 0, stream>>>(bufA, batch, pooled, counts, M);
    final_kernel<<<1, TPB, 0, stream>>>(pooled, counts, a3, c3, Wlin, blin, out, G);
}

// Round 4
// 926.527 us; speedup vs baseline: 5.2018x; 1.1179x over previous
//
#include <hip/hip_runtime.h>
#include <math.h>
#include <stdint.h>

#define TPB 256
#define NF 128          // feature width (all layers)
#define BN_EPS_C 1e-5f
#define BSH 9           // bucket shift: 512 nodes per bucket

typedef __attribute__((ext_vector_type(8))) short bf16x8;   // 8 bf16 (4 VGPRs)
typedef __attribute__((ext_vector_type(4))) float f32x4;    // 4 fp32

// ---------------------------------------------------------------------------
__device__ __forceinline__ void atomAddF(float* p, float v) {
    unsafeAtomicAdd(p, v);
}

// fp32 <-> bf16 (RNE), bit-level
__device__ __forceinline__ short f2bf(float f) {
    unsigned u = __float_as_uint(f);
    unsigned r = (u + 0x7FFFu + ((u >> 16) & 1u)) >> 16;
    return (short)r;
}
__device__ __forceinline__ float bf2f(short b) {
    return __uint_as_float(((unsigned)(unsigned short)b) << 16);
}

// ===========================================================================
// Bucketed CSR build. Buckets of 512 consecutive dst-nodes; per-bucket srcs
// region is ~32KB (L2-resident) so scatter writes stop thrashing HBM.
// ===========================================================================
__global__ __launch_bounds__(TPB) void bucket_count(
    const int* __restrict__ dst, int* __restrict__ bucket_cnt, int E, int nbuck)
{
    __shared__ int h[256];
    h[threadIdx.x] = 0;
    __syncthreads();
    int base = blockIdx.x * 1024;
    int lim = min(base + 1024, E);
    for (int i = base + threadIdx.x; i < lim; i += 256)
        atomicAdd(&h[dst[i] >> BSH], 1);
    __syncthreads();
    if (threadIdx.x < nbuck && h[threadIdx.x])
        atomicAdd(&bucket_cnt[threadIdx.x], h[threadIdx.x]);
}

__global__ __launch_bounds__(TPB) void bucket_scan(
    const int* __restrict__ bucket_cnt, int* __restrict__ boff,
    int* __restrict__ bucket_cur, int nbuck, int E)
{
    __shared__ int s[256];
    int t = threadIdx.x;
    int v = (t < nbuck) ? bucket_cnt[t] : 0;
    s[t] = v;
    __syncthreads();
    for (int off = 1; off < 256; off <<= 1) {
        int x = (t >= off) ? s[t - off] : 0;
        __syncthreads();
        s[t] += x;
        __syncthreads();
    }
    int excl = s[t] - v;
    if (t < nbuck) { boff[t] = excl; bucket_cur[t] = excl; }
    if (t == 0) boff[nbuck] = E;
}

// Partition edges into bucket-ordered (src,dst) pairs; block-aggregated
// cursor reservation -> per-bucket writes are contiguous streams.
__global__ __launch_bounds__(TPB) void partition_edges(
    const int* __restrict__ src, const int* __restrict__ dst,
    int* __restrict__ bucket_cur, int2* __restrict__ pairs, int E, int nbuck)
{
    __shared__ int cnt[256];
    __shared__ int gbase[256];
    int t = threadIdx.x;
    cnt[t] = 0;
    __syncthreads();
    int base = blockIdx.x * 1024;
    int myb[4], myrank[4], mys[4], myd[4];
#pragma unroll
    for (int j = 0; j < 4; ++j) {
        int i = base + j * 256 + t;
        if (i < E) {
            int d = dst[i];
            int b = d >> BSH;
            myb[j] = b; myd[j] = d; mys[j] = src[i];
            myrank[j] = atomicAdd(&cnt[b], 1);
        } else myb[j] = -1;
    }
    __syncthreads();
    if (t < nbuck && cnt[t]) gbase[t] = atomicAdd(&bucket_cur[t], cnt[t]);
    __syncthreads();
#pragma unroll
    for (int j = 0; j < 4; ++j)
        if (myb[j] >= 0)
            pairs[gbase[myb[j]] + myrank[j]] = make_int2(mys[j], myd[j]);
}

// One block per bucket: LDS degree count + LDS scan -> rowptr; then local
// scatter of srcs into the bucket's contiguous (L2-resident) region.
__global__ __launch_bounds__(TPB) void bucket_build(
    const int2* __restrict__ pairs, const int* __restrict__ boff,
    int* __restrict__ rowptr, int* __restrict__ srcs, int M, int E)
{
    __shared__ int ldeg[512];
    __shared__ int lsum[256];
    int b = blockIdx.x;
    int t = threadIdx.x;
    int n0 = b << BSH;
    int nn = min(512, M - n0);
    int p0 = boff[b], p1 = boff[b + 1];
    ldeg[t] = 0; ldeg[t + 256] = 0;
    __syncthreads();
    for (int i = p0 + t; i < p1; i += 256)
        atomicAdd(&ldeg[pairs[i].y - n0], 1);
    __syncthreads();
    int a0 = ldeg[2 * t], a1 = ldeg[2 * t + 1];
    lsum[t] = a0 + a1;
    __syncthreads();
    for (int off = 1; off < 256; off <<= 1) {
        int x = (t >= off) ? lsum[t - off] : 0;
        __syncthreads();
        lsum[t] += x;
        __syncthreads();
    }
    int excl = lsum[t] - (a0 + a1);
    ldeg[2 * t]     = p0 + excl;            // becomes scatter cursor
    ldeg[2 * t + 1] = p0 + excl + a0;
    if (2 * t < nn)     rowptr[n0 + 2 * t]     = p0 + excl;
    if (2 * t + 1 < nn) rowptr[n0 + 2 * t + 1] = p0 + excl + a0;
    if (b == 0 && t == 0) rowptr[M] = E;
    __syncthreads();
    for (int i = p0 + t; i < p1; i += 256) {
        int2 pr = pairs[i];
        int pos = atomicAdd(&ldeg[pr.y - n0], 1);
        srcs[pos] = pr.x;
    }
}

// ===========================================================================
// Gather aggregation v2: one wave per node; each 32-lane half covers a FULL
// 512B row with float4/lane; 4 rows in flight per half (8 edges/wave).
// agg[n] = a * sum_{j in N(n)} h[j] + c * deg(n)   (BN affine distributed)
// ===========================================================================
template<bool NORM>
__global__ __launch_bounds__(TPB) void gather_agg(
    const float* __restrict__ h, const int* __restrict__ rowptr,
    const int* __restrict__ srcs,
    const float* __restrict__ na, const float* __restrict__ nc,
    float* __restrict__ agg, int M)
{
    int wid = (blockIdx.x * TPB + threadIdx.x) >> 6;
    if (wid >= M) return;
    int lane = threadIdx.x & 63;
    int half = lane >> 5;
    int li   = lane & 31;
    int start = rowptr[wid], end = rowptr[wid + 1];

    f32x4 A0 = (f32x4){0.f, 0.f, 0.f, 0.f}, A1 = A0, A2 = A0, A3 = A0;
    int e = start + half;
    for (; e + 6 < end; e += 8) {
        int s0 = srcs[e], s1 = srcs[e + 2], s2 = srcs[e + 4], s3 = srcs[e + 6];
        A0 += *(const f32x4*)(h + (size_t)s0 * NF + li * 4);
        A1 += *(const f32x4*)(h + (size_t)s1 * NF + li * 4);
        A2 += *(const f32x4*)(h + (size_t)s2 * NF + li * 4);
        A3 += *(const f32x4*)(h + (size_t)s3 * NF + li * 4);
    }
    for (; e < end; e += 2)
        A0 += *(const f32x4*)(h + (size_t)srcs[e] * NF + li * 4);
    A0 = (A0 + A1) + (A2 + A3);
    // combine the two half-wave partial sums (even vs odd edges)
    A0.x += __shfl_xor(A0.x, 32);
    A0.y += __shfl_xor(A0.y, 32);
    A0.z += __shfl_xor(A0.z, 32);
    A0.w += __shfl_xor(A0.w, 32);
    if (half == 0) {
        f32x4 res;
        if (NORM) {
            float degf = (float)(end - start);
            f32x4 aa = *(const f32x4*)(na + li * 4);
            f32x4 cc = *(const f32x4*)(nc + li * 4);
            res = A0 * aa + cc * degf;
        } else {
            res = A0;
        }
        *(f32x4*)(agg + (size_t)wid * NF + li * 4) = res;
    }
}

// ===========================================================================
// W prep (all 3 layers in one launch): transpose + concat + split bf16 hi/lo.
// Wt[n][k], k in [0,256): k<128 -> Wr[k][n], else Wroot[k-128][n]
// ===========================================================================
__global__ __launch_bounds__(256) void wsplit_all(
    const float* __restrict__ W1r, const float* __restrict__ W1o,
    const float* __restrict__ W2r, const float* __restrict__ W2o,
    const float* __restrict__ W3r, const float* __restrict__ W3o,
    short* __restrict__ hi, short* __restrict__ lo)
{
    int layer = blockIdx.x >> 7;
    int n = blockIdx.x & 127;
    int k = threadIdx.x;
    const float* Wr = (layer == 0) ? W1r : (layer == 1) ? W2r : W3r;
    const float* Wo = (layer == 0) ? W1o : (layer == 1) ? W2o : W3o;
    float v = (k < NF) ? Wr[k * NF + n] : Wo[(k - NF) * NF + n];
    short h = f2bf(v);
    size_t off = (size_t)layer * 128 * 256 + n * 256 + k;
    hi[off] = h;
    lo[off] = f2bf(v - bf2f(h));
}

// ===========================================================================
// MFMA dual GEMM via split-bf16 (Markidis 3-term):
//   C = [Aagg | norm(Ax)] @ Wt^T + bias  (+ReLU, +fused BN column stats)
// ===========================================================================
template<bool RELU, bool NORM>
__global__ __launch_bounds__(TPB, 2) void gemm_mfma(
    const float* Aagg, const float* Ax,                    // may alias C
    const float* __restrict__ na, const float* __restrict__ nc,
    const short* __restrict__ wt_hi, const short* __restrict__ wt_lo,
    const float* __restrict__ bias, float* C,
    float* __restrict__ gsum, float* __restrict__ gsq, int M)
{
    __shared__ float ssum[16][NF];
    __shared__ float ssq [16][NF];

    const int tid  = threadIdx.x;
    const int wid  = tid >> 6;
    const int lane = tid & 63;
    const int lg   = lane >> 4;        // quad 0..3
    const int ln   = lane & 15;
    const int rowbase = blockIdx.x * 128 + wid * 32;

    f32x4 acc[2][8];
#pragma unroll
    for (int i = 0; i < 2; ++i)
#pragma unroll
        for (int j = 0; j < 8; ++j) acc[i][j] = (f32x4){0.f, 0.f, 0.f, 0.f};

#pragma unroll
    for (int kc = 0; kc < 8; ++kc) {
        const int k0 = kc * 32;                     // concat-K chunk base
        const bool second = (k0 >= NF);
        const int kcol = (second ? k0 - NF : k0) + lg * 8;
        const float* Asrc = second ? Ax : Aagg;

        bf16x8 ahi[2], alo[2];
#pragma unroll
        for (int mt = 0; mt < 2; ++mt) {
            int row = rowbase + mt * 16 + ln;
            f32x4 v0 = (f32x4){0.f, 0.f, 0.f, 0.f};
            f32x4 v1 = v0;
            if (row < M) {
                v0 = *(const f32x4*)(Asrc + (size_t)row * NF + kcol);
                v1 = *(const f32x4*)(Asrc + (size_t)row * NF + kcol + 4);
            }
            if (NORM && second) {
                f32x4 a0 = *(const f32x4*)(na + kcol);
                f32x4 a1 = *(const f32x4*)(na + kcol + 4);
                f32x4 c0 = *(const f32x4*)(nc + kcol);
                f32x4 c1 = *(const f32x4*)(nc + kcol + 4);
                v0 = v0 * a0 + c0;
                v1 = v1 * a1 + c1;
            }
            float vv[8] = {v0.x, v0.y, v0.z, v0.w, v1.x, v1.y, v1.z, v1.w};
#pragma unroll
            for (int j = 0; j < 8; ++j) {
                short h = f2bf(vv[j]);
                ahi[mt][j] = h;
                alo[mt][j] = f2bf(vv[j] - bf2f(h));
            }
        }

#pragma unroll
        for (int nt = 0; nt < 8; ++nt) {
            const size_t wof = (size_t)(nt * 16 + ln) * 256 + k0 + lg * 8;
            bf16x8 bhi = *(const bf16x8*)(wt_hi + wof);
            bf16x8 blo = *(const bf16x8*)(wt_lo + wof);
#pragma unroll
            for (int mt = 0; mt < 2; ++mt) {
                acc[mt][nt] = __builtin_amdgcn_mfma_f32_16x16x32_bf16(ahi[mt], bhi, acc[mt][nt], 0, 0, 0);
                acc[mt][nt] = __builtin_amdgcn_mfma_f32_16x16x32_bf16(alo[mt], bhi, acc[mt][nt], 0, 0, 0);
                acc[mt][nt] = __builtin_amdgcn_mfma_f32_16x16x32_bf16(ahi[mt], blo, acc[mt][nt], 0, 0, 0);
            }
        }
    }

    // ---- epilogue: bias (+ReLU), store, fused BN stats ----
    float s8[8], q8[8];
#pragma unroll
    for (int nt = 0; nt < 8; ++nt) { s8[nt] = 0.f; q8[nt] = 0.f; }

#pragma unroll
    for (int nt = 0; nt < 8; ++nt) {
        int col = nt * 16 + ln;
        float b = bias[col];
#pragma unroll
        for (int mt = 0; mt < 2; ++mt) {
            int rm = rowbase + mt * 16 + lg * 4;
#pragma unroll
            for (int r = 0; r < 4; ++r) {
                int row = rm + r;
                if (row < M) {
                    float v = acc[mt][nt][r] + b;
                    if (RELU) v = fmaxf(v, 0.f);
                    C[(size_t)row * NF + col] = v;
                    s8[nt] += v;
                    q8[nt] += v * v;
                }
            }
        }
    }

    const int rg = wid * 4 + lg;
#pragma unroll
    for (int nt = 0; nt < 8; ++nt) {
        ssum[rg][nt * 16 + ln] = s8[nt];
        ssq [rg][nt * 16 + ln] = q8[nt];
    }
    __syncthreads();
    if (tid < NF) {
        float s = 0.f, q = 0.f;
#pragma unroll
        for (int g = 0; g < 16; ++g) { s += ssum[g][tid]; q += ssq[g][tid]; }
        atomAddF(&gsum[tid], s);
        atomAddF(&gsq[tid], q);
    }
}

// Fold BN into affine: a = gamma*rsqrt(var+eps), c = beta - mean*a
__global__ __launch_bounds__(128) void bn_finalize(
    const float* __restrict__ gsum, const float* __restrict__ gsq,
    const float* __restrict__ gamma, const float* __restrict__ beta,
    float* __restrict__ a, float* __restrict__ c, int M)
{
    int k = threadIdx.x;
    float invM = 1.0f / (float)M;
    float mean = gsum[k] * invM;
    float var  = fmaxf(gsq[k] * invM - mean * mean, 0.f);
    float s    = gamma[k] / sqrtf(var + BN_EPS_C);
    a[k] = s;
    c[k] = beta[k] - mean * s;
}

// ---------------------------------------------------------------------------
// Pooling: batch is SORTED -> run-length accumulate, flush per run per block.
// ---------------------------------------------------------------------------
__global__ __launch_bounds__(TPB) void pool_kernel(
    const float* __restrict__ h, const int* __restrict__ batch,
    float* __restrict__ pooled, float* __restrict__ counts, int M)
{
    int base = blockIdx.x * 128;
    int col  = threadIdx.x & 127;
    int half = threadIdx.x >> 7;
    int end  = min(base + 128, M);
    float acc = 0.f; int cnt = 0; int gcur = -1;
    for (int n = base + half; n < end; n += 2) {
        int g = batch[n];
        if (g != gcur) {
            if (gcur >= 0) {
                atomAddF(&pooled[(size_t)gcur * NF + col], acc);
                if (col == 0) atomAddF(&counts[gcur], (float)cnt);
            }
            acc = 0.f; cnt = 0; gcur = g;
        }
        acc += h[(size_t)n * NF + col];
        cnt += 1;
    }
    if (gcur >= 0) {
        atomAddF(&pooled[(size_t)gcur * NF + col], acc);
        if (col == 0) atomAddF(&counts[gcur], (float)cnt);
    }
}

__global__ __launch_bounds__(TPB) void final_kernel(
    const float* __restrict__ pooled, const float* __restrict__ counts,
    const float* __restrict__ a3, const float* __restrict__ c3,
    const float* __restrict__ Wlin, const float* __restrict__ blin,
    float* __restrict__ out, int G)
{
    int g = threadIdx.x;
    if (g >= G) return;
    float cntRaw = counts[g];
    float inv = 1.0f / fmaxf(cntRaw, 1.0f);
    float nonEmpty = cntRaw > 0.5f ? 1.0f : 0.0f;
    float acc0 = 0.f, acc1 = 0.f;
    for (int k = 0; k < NF; ++k) {
        float v = (a3[k] * pooled[(size_t)g * NF + k] * inv + c3[k]) * nonEmpty;
        acc0 += v * Wlin[k * 2 + 0];
        acc1 += v * Wlin[k * 2 + 1];
    }
    out[g * 2 + 0] = acc0 + blin[0];
    out[g * 2 + 1] = acc1 + blin[1];
}

// ---------------------------------------------------------------------------
extern "C" void kernel_launch(void* const* d_in, const int* in_sizes, int n_in,
                              void* d_out, int out_size, void* d_ws, size_t ws_size,
                              hipStream_t stream)
{
    const float* x     = (const float*)d_in[0];
    const int*   eidx  = (const int*)d_in[1];
    const int*   batch = (const int*)d_in[2];
    const float* W1r = (const float*)d_in[3],  *b1 = (const float*)d_in[4];
    const float* W1o = (const float*)d_in[5],  *g1 = (const float*)d_in[6],  *be1 = (const float*)d_in[7];
    const float* W2r = (const float*)d_in[8],  *b2 = (const float*)d_in[9];
    const float* W2o = (const float*)d_in[10], *g2 = (const float*)d_in[11], *be2 = (const float*)d_in[12];
    const float* W3r = (const float*)d_in[13], *b3 = (const float*)d_in[14];
    const float* W3o = (const float*)d_in[15], *g3 = (const float*)d_in[16], *be3 = (const float*)d_in[17];
    const float* Wlin = (const float*)d_in[18], *blin = (const float*)d_in[19];
    float* out = (float*)d_out;

    const int M = in_sizes[0] / NF;        // 100000 nodes
    const int E = in_sizes[1] / 2;         // 1.6M edges
    const int G = out_size / 2;            // 256 graphs
    const int* src = eidx;
    const int* dst = eidx + E;
    const int nbuck = (M + 511) >> BSH;

    const size_t NODEF = (size_t)M * NF;

    // ---- workspace layout ----
    float* bufA = (float*)d_ws;                    // NODEF
    float* bufB = bufA + NODEF;                    // NODEF
    float* zf   = bufB + NODEF;                    // zeroed float zone
    float* gsum1 = zf;        float* gsq1 = zf + 128;
    float* gsum2 = zf + 256;  float* gsq2 = zf + 384;
    float* gsum3 = zf + 512;  float* gsq3 = zf + 640;
    float* counts = zf + 768;                      // G
    float* pooled = counts + G;                    // G*NF
    int*   zi   = (int*)(pooled + (size_t)G * NF); // zeroed int zone (1024)
    int* bucket_cnt = zi;                          // 256
    int* bucket_cur = zi + 256;                    // 256
    int* boff       = zi + 512;                    // nbuck+1 (<=257)
    int* ziEnd      = zi + 1024;
    float* ac = (float*)ziEnd;                     // 768: a/c per layer
    float* a1 = ac;       float* c1 = ac + 128;
    float* a2 = ac + 256; float* c2 = ac + 384;
    float* a3 = ac + 512; float* c3 = ac + 640;
    int* rowptr = (int*)(ac + 768);                // M+1
    int* srcs   = rowptr + (M + 1);                // E
    uintptr_t pp = ((uintptr_t)(srcs + E) + 15) & ~(uintptr_t)15;
    int2* pairs = (int2*)pp;                       // E (CSR build only)
    // wt buffers UNION with pairs (pairs dead before wsplit runs)
    short* wt_hi = (short*)pp;                     // 3*128*256
    short* wt_lo = wt_hi + 3 * 128 * 256;          // 3*128*256

    const int gridE1024   = (E + 1023) / 1024;
    const int gatherBlocks = (int)(((size_t)M * 64 + TPB - 1) / TPB);
    const int gemmBlocks   = (M + 127) / 128;
    const int poolBlocks   = (M + 127) / 128;

    // single memset: float zone + int zone
    size_t zbytes = (char*)ziEnd - (char*)zf;
    hipMemsetAsync(zf, 0, zbytes, stream);

    // ---- bucketed reverse-CSR build (dst-grouped), reused by all 3 layers
    bucket_count   <<<gridE1024, TPB, 0, stream>>>(dst, bucket_cnt, E, nbuck);
    bucket_scan    <<<1, TPB, 0, stream>>>(bucket_cnt, boff, bucket_cur, nbuck, E);
    partition_edges<<<gridE1024, TPB, 0, stream>>>(src, dst, bucket_cur, pairs, E, nbuck);
    bucket_build   <<<nbuck, TPB, 0, stream>>>(pairs, boff, rowptr, srcs, M, E);

    // ---- W prep (after CSR: wt aliases pairs)
    wsplit_all<<<384, 256, 0, stream>>>(W1r, W1o, W2r, W2o, W3r, W3o, wt_hi, wt_lo);

    // ---- layer 1
    gather_agg<false><<<gatherBlocks, TPB, 0, stream>>>(x, rowptr, srcs, nullptr, nullptr, bufA, M);
    gemm_mfma<true, false><<<gemmBlocks, TPB, 0, stream>>>(
        bufA, x, nullptr, nullptr, wt_hi, wt_lo, b1, bufA, gsum1, gsq1, M);
    bn_finalize<<<1, 128, 0, stream>>>(gsum1, gsq1, g1, be1, a1, c1, M);

    // ---- layer 2
    gather_agg<true><<<gatherBlocks, TPB, 0, stream>>>(bufA, rowptr, srcs, a1, c1, bufB, M);
    gemm_mfma<true, true><<<gemmBlocks, TPB, 0, stream>>>(
        bufB, bufA, a1, c1, wt_hi + 32768, wt_lo + 32768, b2, bufB, gsum2, gsq2, M);
    bn_finalize<<<1, 128, 0, stream>>>(gsum2, gsq2, g2, be2, a2, c2, M);

    // ---- layer 3 (no ReLU)
    gather_agg<true><<<gatherBlocks, TPB, 0, stream>>>(bufB, rowptr, srcs, a2, c2, bufA, M);
    gemm_mfma<false, true><<<gemmBlocks, TPB, 0, stream>>>(
        bufA, bufB, a2, c2, wt_hi + 65536, wt_lo + 65536, b3, bufA, gsum3, gsq3, M);
    bn_finalize<<<1, 128, 0, stream>>>(gsum3, gsq3, g3, be3, a3, c3, M);

    // ---- pool + classify
    pool_kernel<<<poolBlocks, TPB, 0, stream>>>(bufA, batch, pooled, counts, M);
    final_kernel<<<1, TPB, 0, stream>>>(pooled, counts, a3, c3, Wlin, blin, out, G);
}

// Round 5
// 855.255 us; speedup vs baseline: 5.6353x; 1.0833x over previous
//
#include <hip/hip_runtime.h>
#include <math.h>
#include <stdint.h>

#define TPB 256
#define NF 128          // feature width (all layers)
#define BN_EPS_C 1e-5f
#define BSH 9           // bucket shift: 512 nodes per bucket

typedef __attribute__((ext_vector_type(8))) short bf16x8;   // 8 bf16 (4 VGPRs)
typedef __attribute__((ext_vector_type(4))) float f32x4;    // 4 fp32

// ---------------------------------------------------------------------------
__device__ __forceinline__ void atomAddF(float* p, float v) {
    unsafeAtomicAdd(p, v);
}

// fp32 <-> bf16 (RNE), bit-level
__device__ __forceinline__ short f2bf(float f) {
    unsigned u = __float_as_uint(f);
    unsigned r = (u + 0x7FFFu + ((u >> 16) & 1u)) >> 16;
    return (short)r;
}
__device__ __forceinline__ float bf2f(short b) {
    return __uint_as_float(((unsigned)(unsigned short)b) << 16);
}

// async 16B global -> LDS DMA (global_load_lds dwordx4)
__device__ __forceinline__ void async_copy16(const float* g, float* l) {
    __builtin_amdgcn_global_load_lds(
        (const __attribute__((address_space(1))) unsigned int*)g,
        (__attribute__((address_space(3))) unsigned int*)l, 16, 0, 0);
}

// ===========================================================================
// Bucketed CSR build (dst-grouped). Per-bucket srcs region is ~32KB
// (L2-resident) so scatter writes don't thrash HBM.
// ===========================================================================
__global__ __launch_bounds__(TPB) void bucket_count(
    const int* __restrict__ dst, int* __restrict__ bucket_cnt, int E, int nbuck)
{
    __shared__ int h[256];
    h[threadIdx.x] = 0;
    __syncthreads();
    int base = blockIdx.x * 1024;
    int lim = min(base + 1024, E);
    for (int i = base + threadIdx.x; i < lim; i += 256)
        atomicAdd(&h[dst[i] >> BSH], 1);
    __syncthreads();
    if (threadIdx.x < nbuck && h[threadIdx.x])
        atomicAdd(&bucket_cnt[threadIdx.x], h[threadIdx.x]);
}

__global__ __launch_bounds__(TPB) void bucket_scan(
    const int* __restrict__ bucket_cnt, int* __restrict__ boff,
    int* __restrict__ bucket_cur, int nbuck, int E)
{
    __shared__ int s[256];
    int t = threadIdx.x;
    int v = (t < nbuck) ? bucket_cnt[t] : 0;
    s[t] = v;
    __syncthreads();
    for (int off = 1; off < 256; off <<= 1) {
        int x = (t >= off) ? s[t - off] : 0;
        __syncthreads();
        s[t] += x;
        __syncthreads();
    }
    int excl = s[t] - v;
    if (t < nbuck) { boff[t] = excl; bucket_cur[t] = excl; }
    if (t == 0) boff[nbuck] = E;
}

__global__ __launch_bounds__(TPB) void partition_edges(
    const int* __restrict__ src, const int* __restrict__ dst,
    int* __restrict__ bucket_cur, int2* __restrict__ pairs, int E, int nbuck)
{
    __shared__ int cnt[256];
    __shared__ int gbase[256];
    int t = threadIdx.x;
    cnt[t] = 0;
    __syncthreads();
    int base = blockIdx.x * 1024;
    int myb[4], myrank[4], mys[4], myd[4];
#pragma unroll
    for (int j = 0; j < 4; ++j) {
        int i = base + j * 256 + t;
        if (i < E) {
            int d = dst[i];
            int b = d >> BSH;
            myb[j] = b; myd[j] = d; mys[j] = src[i];
            myrank[j] = atomicAdd(&cnt[b], 1);
        } else myb[j] = -1;
    }
    __syncthreads();
    if (t < nbuck && cnt[t]) gbase[t] = atomicAdd(&bucket_cur[t], cnt[t]);
    __syncthreads();
#pragma unroll
    for (int j = 0; j < 4; ++j)
        if (myb[j] >= 0)
            pairs[gbase[myb[j]] + myrank[j]] = make_int2(mys[j], myd[j]);
}

// One block per bucket: LDS degree count + scan -> rowptr + degf; local
// scatter of srcs into the bucket's contiguous region.
__global__ __launch_bounds__(TPB) void bucket_build(
    const int2* __restrict__ pairs, const int* __restrict__ boff,
    int* __restrict__ rowptr, int* __restrict__ srcs,
    float* __restrict__ degf, int M, int E)
{
    __shared__ int ldeg[512];
    __shared__ int lsum[256];
    int b = blockIdx.x;
    int t = threadIdx.x;
    int n0 = b << BSH;
    int nn = min(512, M - n0);
    int p0 = boff[b], p1 = boff[b + 1];
    ldeg[t] = 0; ldeg[t + 256] = 0;
    __syncthreads();
    for (int i = p0 + t; i < p1; i += 256)
        atomicAdd(&ldeg[pairs[i].y - n0], 1);
    __syncthreads();
    int a0 = ldeg[2 * t], a1 = ldeg[2 * t + 1];
    lsum[t] = a0 + a1;
    __syncthreads();
    for (int off = 1; off < 256; off <<= 1) {
        int x = (t >= off) ? lsum[t - off] : 0;
        __syncthreads();
        lsum[t] += x;
        __syncthreads();
    }
    int excl = lsum[t] - (a0 + a1);
    ldeg[2 * t]     = p0 + excl;            // becomes scatter cursor
    ldeg[2 * t + 1] = p0 + excl + a0;
    if (2 * t < nn)     { rowptr[n0 + 2 * t]     = p0 + excl;      degf[n0 + 2 * t]     = (float)a0; }
    if (2 * t + 1 < nn) { rowptr[n0 + 2 * t + 1] = p0 + excl + a0; degf[n0 + 2 * t + 1] = (float)a1; }
    if (b == 0 && t == 0) rowptr[M] = E;
    __syncthreads();
    for (int i = p0 + t; i < p1; i += 256) {
        int2 pr = pairs[i];
        int pos = atomicAdd(&ldeg[pr.y - n0], 1);
        srcs[pos] = pr.x;
    }
}

// ===========================================================================
// Gather aggregation (RAW sums now — BN folded into next GEMM's weights):
// one wave per node; each 32-lane half covers a full 512B row (float4/lane).
// ===========================================================================
__global__ __launch_bounds__(TPB) void gather_agg(
    const float* __restrict__ h, const int* __restrict__ rowptr,
    const int* __restrict__ srcs, float* __restrict__ agg, int M)
{
    int wid = (blockIdx.x * TPB + threadIdx.x) >> 6;
    if (wid >= M) return;
    int lane = threadIdx.x & 63;
    int half = lane >> 5;
    int li   = lane & 31;
    int start = rowptr[wid], end = rowptr[wid + 1];

    f32x4 A0 = (f32x4){0.f, 0.f, 0.f, 0.f}, A1 = A0, A2 = A0, A3 = A0;
    int e = start + half;
    for (; e + 6 < end; e += 8) {
        int s0 = srcs[e], s1 = srcs[e + 2], s2 = srcs[e + 4], s3 = srcs[e + 6];
        A0 += *(const f32x4*)(h + (size_t)s0 * NF + li * 4);
        A1 += *(const f32x4*)(h + (size_t)s1 * NF + li * 4);
        A2 += *(const f32x4*)(h + (size_t)s2 * NF + li * 4);
        A3 += *(const f32x4*)(h + (size_t)s3 * NF + li * 4);
    }
    for (; e < end; e += 2)
        A0 += *(const f32x4*)(h + (size_t)srcs[e] * NF + li * 4);
    A0 = (A0 + A1) + (A2 + A3);
    A0.x += __shfl_xor(A0.x, 32);
    A0.y += __shfl_xor(A0.y, 32);
    A0.z += __shfl_xor(A0.z, 32);
    A0.w += __shfl_xor(A0.w, 32);
    if (half == 0)
        *(f32x4*)(agg + (size_t)wid * NF + li * 4) = A0;
}

// ===========================================================================
// Layer-1 W prep: transpose + concat + split bf16 hi/lo (no norm).
// Wt[n][k], k in [0,256): k<128 -> Wr[k][n], else Wroot[k-128][n]
// ===========================================================================
__global__ __launch_bounds__(256) void wsplit_kernel(
    const float* __restrict__ Wr, const float* __restrict__ Wo,
    short* __restrict__ hi, short* __restrict__ lo)
{
    int n = blockIdx.x;      // 0..127
    int k = threadIdx.x;     // 0..255
    float v = (k < NF) ? Wr[k * NF + n] : Wo[(k - NF) * NF + n];
    short h = f2bf(v);
    hi[n * 256 + k] = h;
    lo[n * 256 + k] = f2bf(v - bf2f(h));
}

// ===========================================================================
// Fold BN affine (a,c) of the previous layer into this layer's weights:
//   Wt[n][k<128]  = a[k]  * Wr[k][n]     (agg path)
//   Wt[n][k>=128] = a[kk] * Wroot[kk][n] (root path)
//   dvec[n]  = sum_k c[k]*Wr[k][n]       (multiplied by deg_i in epilogue)
//   bias2[n] = b[n] + sum_k c[k]*Wroot[k][n]
// ===========================================================================
__global__ __launch_bounds__(256) void fold_kernel(
    const float* __restrict__ a, const float* __restrict__ c,
    const float* __restrict__ Wr, const float* __restrict__ Wo,
    const float* __restrict__ b,
    short* __restrict__ hi, short* __restrict__ lo,
    float* __restrict__ bias2, float* __restrict__ dvec)
{
    __shared__ float red[256];
    int n = blockIdx.x;
    int k = threadIdx.x;
    float w, contrib;
    if (k < NF) { w = Wr[k * NF + n];          contrib = c[k] * w;       w *= a[k]; }
    else        { int kk = k - NF; w = Wo[kk * NF + n]; contrib = c[kk] * w; w *= a[kk]; }
    short h = f2bf(w);
    hi[n * 256 + k] = h;
    lo[n * 256 + k] = f2bf(w - bf2f(h));
    red[k] = contrib;
    __syncthreads();
    for (int off = 64; off >= 1; off >>= 1) {
        if ((k & 127) < off) red[k] += red[k + off];
        __syncthreads();
    }
    if (k == 0)   dvec[n]  = red[0];
    if (k == 128) bias2[n] = b[n] + red[128];
}

// ===========================================================================
// MFMA dual GEMM v2 (LDS-staged A via global_load_lds, split-bf16 3-term):
//   C = [S | h] @ Wt^T + bias (+deg_i*dvec if NORM) (+ReLU) (+BN stats)
// A-chunks (128 rows x 32 k, 16 KB) DMA'd to LDS with 16B XOR swizzle
// (lds_seg = glob_seg ^ (row&7)) -> ds_read_b128 frags are 2-way-conflict
// only. Block=256thr=4 waves; wave = 32 rows x 128 cols (2x8 16x16 tiles).
// C may alias S (block writes only its own fully-consumed 128-row stripe).
// ===========================================================================
template<bool RELU, bool NORM>
__global__ __launch_bounds__(TPB) void gemm_mfma(
    const float* Aagg, const float* Ax,                    // may alias C
    const short* __restrict__ wt_hi, const short* __restrict__ wt_lo,
    const float* __restrict__ bias, const float* __restrict__ dvec,
    const float* __restrict__ degf, float* C,
    float* __restrict__ gsum, float* __restrict__ gsq, int M)
{
    __shared__ float sA[4096];         // 16 KB chunk buffer; reused for stats

    const int tid  = threadIdx.x;
    const int wid  = tid >> 6;
    const int lane = tid & 63;
    const int lg   = lane >> 4;        // quad 0..3
    const int ln   = lane & 15;
    const int m0   = blockIdx.x * 128;
    const int rowbase = m0 + wid * 32;

    f32x4 acc[2][8];
#pragma unroll
    for (int i = 0; i < 2; ++i)
#pragma unroll
        for (int j = 0; j < 8; ++j) acc[i][j] = (f32x4){0.f, 0.f, 0.f, 0.f};

#pragma unroll
    for (int kc = 0; kc < 8; ++kc) {
        const float* Asrc = (kc < 4) ? Aagg : Ax;
        const int kbase = (kc & 3) * 32;            // float offset in source row

        __syncthreads();                // prior chunk fully consumed
        // ---- DMA chunk into LDS (swizzled at 16B granularity)
#pragma unroll
        for (int is = 0; is < 4; ++is) {
            int seg  = is * 256 + tid;              // 0..1023
            int row  = seg >> 3;                    // 0..127 (local)
            int kgs  = seg & 7;                     // LDS 16B slot in row
            int kgg  = kgs ^ (row & 7);             // global 16B slot (swizzle)
            int rowg = min(m0 + row, M - 1);        // clamp (results discarded)
            async_copy16(Asrc + (size_t)rowg * NF + kbase + kgg * 4, sA + seg * 4);
        }
        __syncthreads();                // compiler drains vmcnt before barrier

        // ---- fragments + MFMA
        const int k0 = kc * 32;                     // concat-K base (for W)
        bf16x8 ahi[2], alo[2];
#pragma unroll
        for (int mt = 0; mt < 2; ++mt) {
            int lrow = wid * 32 + mt * 16 + ln;
            int r7 = lrow & 7;
            f32x4 p0 = *(const f32x4*)(sA + lrow * 32 + (((lg * 2 + 0) ^ r7) << 2));
            f32x4 p1 = *(const f32x4*)(sA + lrow * 32 + (((lg * 2 + 1) ^ r7) << 2));
            float vv[8] = {p0.x, p0.y, p0.z, p0.w, p1.x, p1.y, p1.z, p1.w};
#pragma unroll
            for (int j = 0; j < 8; ++j) {
                short h = f2bf(vv[j]);
                ahi[mt][j] = h;
                alo[mt][j] = f2bf(vv[j] - bf2f(h));
            }
        }
#pragma unroll
        for (int nt = 0; nt < 8; ++nt) {
            const size_t wof = (size_t)(nt * 16 + ln) * 256 + k0 + lg * 8;
            bf16x8 bhi = *(const bf16x8*)(wt_hi + wof);
            bf16x8 blo = *(const bf16x8*)(wt_lo + wof);
#pragma unroll
            for (int mt = 0; mt < 2; ++mt) {
                acc[mt][nt] = __builtin_amdgcn_mfma_f32_16x16x32_bf16(ahi[mt], bhi, acc[mt][nt], 0, 0, 0);
                acc[mt][nt] = __builtin_amdgcn_mfma_f32_16x16x32_bf16(alo[mt], bhi, acc[mt][nt], 0, 0, 0);
                acc[mt][nt] = __builtin_amdgcn_mfma_f32_16x16x32_bf16(ahi[mt], blo, acc[mt][nt], 0, 0, 0);
            }
        }
    }

    // ---- epilogue: bias (+deg*dvec) (+ReLU), store, fused BN stats ----
    float B_[8], D_[8];
#pragma unroll
    for (int nt = 0; nt < 8; ++nt) {
        B_[nt] = bias[nt * 16 + ln];
        D_[nt] = NORM ? dvec[nt * 16 + ln] : 0.f;
    }
    float s8[8], q8[8];
#pragma unroll
    for (int nt = 0; nt < 8; ++nt) { s8[nt] = 0.f; q8[nt] = 0.f; }

#pragma unroll
    for (int mt = 0; mt < 2; ++mt) {
#pragma unroll
        for (int r = 0; r < 4; ++r) {
            int row = rowbase + mt * 16 + lg * 4 + r;
            if (row < M) {
                float dg = NORM ? degf[row] : 0.f;
#pragma unroll
                for (int nt = 0; nt < 8; ++nt) {
                    float v = acc[mt][nt][r] + B_[nt];
                    if (NORM) v += dg * D_[nt];
                    if (RELU) v = fmaxf(v, 0.f);
                    C[(size_t)row * NF + nt * 16 + ln] = v;
                    s8[nt] += v;
                    q8[nt] += v * v;
                }
            }
        }
    }

    __syncthreads();                   // done with sA as A-buffer
    float* ssum = sA;                  // [16][128]
    float* ssq  = sA + 2048;
    const int rg = wid * 4 + lg;
#pragma unroll
    for (int nt = 0; nt < 8; ++nt) {
        ssum[rg * NF + nt * 16 + ln] = s8[nt];
        ssq [rg * NF + nt * 16 + ln] = q8[nt];
    }
    __syncthreads();
    if (tid < NF) {
        float s = 0.f, q = 0.f;
#pragma unroll
        for (int g = 0; g < 16; ++g) { s += ssum[g * NF + tid]; q += ssq[g * NF + tid]; }
        atomAddF(&gsum[tid], s);
        atomAddF(&gsq[tid], q);
    }
}

// Fold BN into affine: a = gamma*rsqrt(var+eps), c = beta - mean*a
__global__ __launch_bounds__(128) void bn_finalize(
    const float* __restrict__ gsum, const float* __restrict__ gsq,
    const float* __restrict__ gamma, const float* __restrict__ beta,
    float* __restrict__ a, float* __restrict__ c, int M)
{
    int k = threadIdx.x;
    float invM = 1.0f / (float)M;
    float mean = gsum[k] * invM;
    float var  = fmaxf(gsq[k] * invM - mean * mean, 0.f);
    float s    = gamma[k] / sqrtf(var + BN_EPS_C);
    a[k] = s;
    c[k] = beta[k] - mean * s;
}

// ---------------------------------------------------------------------------
// Pooling: batch is SORTED -> run-length accumulate, flush per run per block.
// ---------------------------------------------------------------------------
__global__ __launch_bounds__(TPB) void pool_kernel(
    const float* __restrict__ h, const int* __restrict__ batch,
    float* __restrict__ pooled, float* __restrict__ counts, int M)
{
    int base = blockIdx.x * 128;
    int col  = threadIdx.x & 127;
    int half = threadIdx.x >> 7;
    int end  = min(base + 128, M);
    float acc = 0.f; int cnt = 0; int gcur = -1;
    for (int n = base + half; n < end; n += 2) {
        int g = batch[n];
        if (g != gcur) {
            if (gcur >= 0) {
                atomAddF(&pooled[(size_t)gcur * NF + col], acc);
                if (col == 0) atomAddF(&counts[gcur], (float)cnt);
            }
            acc = 0.f; cnt = 0; gcur = g;
        }
        acc += h[(size_t)n * NF + col];
        cnt += 1;
    }
    if (gcur >= 0) {
        atomAddF(&pooled[(size_t)gcur * NF + col], acc);
        if (col == 0) atomAddF(&counts[gcur], (float)cnt);
    }
}

__global__ __launch_bounds__(TPB) void final_kernel(
    const float* __restrict__ pooled, const float* __restrict__ counts,
    const float* __restrict__ a3, const float* __restrict__ c3,
    const float* __restrict__ Wlin, const float* __restrict__ blin,
    float* __restrict__ out, int G)
{
    int g = threadIdx.x;
    if (g >= G) return;
    float cntRaw = counts[g];
    float inv = 1.0f / fmaxf(cntRaw, 1.0f);
    float nonEmpty = cntRaw > 0.5f ? 1.0f : 0.0f;
    float acc0 = 0.f, acc1 = 0.f;
    for (int k = 0; k < NF; ++k) {
        float v = (a3[k] * pooled[(size_t)g * NF + k] * inv + c3[k]) * nonEmpty;
        acc0 += v * Wlin[k * 2 + 0];
        acc1 += v * Wlin[k * 2 + 1];
    }
    out[g * 2 + 0] = acc0 + blin[0];
    out[g * 2 + 1] = acc1 + blin[1];
}

// ---------------------------------------------------------------------------
extern "C" void kernel_launch(void* const* d_in, const int* in_sizes, int n_in,
                              void* d_out, int out_size, void* d_ws, size_t ws_size,
                              hipStream_t stream)
{
    const float* x     = (const float*)d_in[0];
    const int*   eidx  = (const int*)d_in[1];
    const int*   batch = (const int*)d_in[2];
    const float* W1r = (const float*)d_in[3],  *b1 = (const float*)d_in[4];
    const float* W1o = (const float*)d_in[5],  *g1 = (const float*)d_in[6],  *be1 = (const float*)d_in[7];
    const float* W2r = (const float*)d_in[8],  *b2 = (const float*)d_in[9];
    const float* W2o = (const float*)d_in[10], *g2 = (const float*)d_in[11], *be2 = (const float*)d_in[12];
    const float* W3r = (const float*)d_in[13], *b3 = (const float*)d_in[14];
    const float* W3o = (const float*)d_in[15], *g3 = (const float*)d_in[16], *be3 = (const float*)d_in[17];
    const float* Wlin = (const float*)d_in[18], *blin = (const float*)d_in[19];
    float* out = (float*)d_out;

    const int M = in_sizes[0] / NF;        // 100000 nodes
    const int E = in_sizes[1] / 2;         // 1.6M edges
    const int G = out_size / 2;            // 256 graphs
    const int* src = eidx;
    const int* dst = eidx + E;
    const int nbuck = (M + 511) >> BSH;

    const size_t NODEF = (size_t)M * NF;

    // ---- workspace layout ----
    float* bufA = (float*)d_ws;                    // NODEF
    float* bufB = bufA + NODEF;                    // NODEF
    float* zf   = bufB + NODEF;                    // zeroed float zone
    float* gsum1 = zf;        float* gsq1 = zf + 128;
    float* gsum2 = zf + 256;  float* gsq2 = zf + 384;
    float* gsum3 = zf + 512;  float* gsq3 = zf + 640;
    float* counts = zf + 768;                      // G
    float* pooled = counts + G;                    // G*NF
    int*   zi   = (int*)(pooled + (size_t)G * NF); // zeroed int zone (1024)
    int* bucket_cnt = zi;                          // 256
    int* bucket_cur = zi + 256;                    // 256
    int* boff       = zi + 512;                    // nbuck+1 (<=257)
    int* ziEnd      = zi + 1024;
    float* ac = (float*)ziEnd;                     // a/c per layer + fold outs
    float* a1 = ac;       float* c1 = ac + 128;
    float* a2 = ac + 256; float* c2 = ac + 384;
    float* a3 = ac + 512; float* c3 = ac + 640;
    float* bias2_2 = ac + 768;  float* dvec2 = ac + 896;
    float* bias2_3 = ac + 1024; float* dvec3 = ac + 1152;
    int* rowptr = (int*)(ac + 1280);               // M+1
    int* srcs   = rowptr + (M + 1);                // E
    float* degf = (float*)(srcs + E);              // M
    uintptr_t pp = ((uintptr_t)(degf + M) + 15) & ~(uintptr_t)15;
    int2* pairs = (int2*)pp;                       // E (CSR build only)
    // wt buffers UNION with pairs (pairs dead before wsplit/fold run)
    short* wt1_hi = (short*)pp;                    // each plane 128*256
    short* wt1_lo = wt1_hi + 32768;
    short* wt2_hi = wt1_hi + 65536;
    short* wt2_lo = wt1_hi + 98304;
    short* wt3_hi = wt1_hi + 131072;
    short* wt3_lo = wt1_hi + 163840;

    const int gridE1024    = (E + 1023) / 1024;
    const int gatherBlocks = (int)(((size_t)M * 64 + TPB - 1) / TPB);
    const int gemmBlocks   = (M + 127) / 128;
    const int poolBlocks   = (M + 127) / 128;

    // single memset: float zone + int zone
    size_t zbytes = (char*)ziEnd - (char*)zf;
    hipMemsetAsync(zf, 0, zbytes, stream);

    // ---- bucketed reverse-CSR build (dst-grouped), reused by all 3 layers
    bucket_count   <<<gridE1024, TPB, 0, stream>>>(dst, bucket_cnt, E, nbuck);
    bucket_scan    <<<1, TPB, 0, stream>>>(bucket_cnt, boff, bucket_cur, nbuck, E);
    partition_edges<<<gridE1024, TPB, 0, stream>>>(src, dst, bucket_cur, pairs, E, nbuck);
    bucket_build   <<<nbuck, TPB, 0, stream>>>(pairs, boff, rowptr, srcs, degf, M, E);

    // ---- layer 1 (no incoming norm: plain split weights)
    wsplit_kernel<<<128, 256, 0, stream>>>(W1r, W1o, wt1_hi, wt1_lo);
    gather_agg<<<gatherBlocks, TPB, 0, stream>>>(x, rowptr, srcs, bufA, M);
    gemm_mfma<true, false><<<gemmBlocks, TPB, 0, stream>>>(
        bufA, x, wt1_hi, wt1_lo, b1, nullptr, nullptr, bufA, gsum1, gsq1, M);
    bn_finalize<<<1, 128, 0, stream>>>(gsum1, gsq1, g1, be1, a1, c1, M);

    // ---- layer 2 (norm1 folded into weights)
    fold_kernel<<<128, 256, 0, stream>>>(a1, c1, W2r, W2o, b2, wt2_hi, wt2_lo, bias2_2, dvec2);
    gather_agg<<<gatherBlocks, TPB, 0, stream>>>(bufA, rowptr, srcs, bufB, M);
    gemm_mfma<true, true><<<gemmBlocks, TPB, 0, stream>>>(
        bufB, bufA, wt2_hi, wt2_lo, bias2_2, dvec2, degf, bufB, gsum2, gsq2, M);
    bn_finalize<<<1, 128, 0, stream>>>(gsum2, gsq2, g2, be2, a2, c2, M);

    // ---- layer 3 (no ReLU; norm2 folded into weights)
    fold_kernel<<<128, 256, 0, stream>>>(a2, c2, W3r, W3o, b3, wt3_hi, wt3_lo, bias2_3, dvec3);
    gather_agg<<<gatherBlocks, TPB, 0, stream>>>(bufB, rowptr, srcs, bufA, M);
    gemm_mfma<false, true><<<gemmBlocks, TPB, 0, stream>>>(
        bufA, bufB, wt3_hi, wt3_lo, bias2_3, dvec3, degf, bufA, gsum3, gsq3, M);
    bn_finalize<<<1, 128, 0, stream>>>(gsum3, gsq3, g3, be3, a3, c3, M);

    // ---- pool + classify (norm3 applied on pooled means)
    pool_kernel<<<poolBlocks, TPB, 0, stream>>>(bufA, batch, pooled, counts, M);
    final_kernel<<<1, TPB, 0, stream>>>(pooled, counts, a3, c3, Wlin, blin, out, G);
}

// Round 6
// 702.641 us; speedup vs baseline: 6.8593x; 1.2172x over previous
//
#include <hip/hip_runtime.h>
#include <math.h>
#include <stdint.h>

#define TPB 256
#define NF 128          // feature width (all layers)
#define BN_EPS_C 1e-5f
#define BSH 9           // bucket shift: 512 nodes per bucket

typedef __attribute__((ext_vector_type(8))) short bf16x8;   // 8 bf16 (4 VGPRs)
typedef __attribute__((ext_vector_type(4))) float f32x4;    // 4 fp32

// ---------------------------------------------------------------------------
__device__ __forceinline__ void atomAddF(float* p, float v) {
    unsafeAtomicAdd(p, v);
}

// fp32 <-> bf16 (RNE), bit-level
__device__ __forceinline__ short f2bf(float f) {
    unsigned u = __float_as_uint(f);
    unsigned r = (u + 0x7FFFu + ((u >> 16) & 1u)) >> 16;
    return (short)r;
}
__device__ __forceinline__ float bf2f(short b) {
    return __uint_as_float(((unsigned)(unsigned short)b) << 16);
}
__device__ __forceinline__ float bflo(unsigned u) { return __uint_as_float(u << 16); }
__device__ __forceinline__ float bfhi(unsigned u) { return __uint_as_float(u & 0xffff0000u); }
__device__ __forceinline__ unsigned packbf(float lo, float hi) {
    return (unsigned)(unsigned short)f2bf(lo) | ((unsigned)(unsigned short)f2bf(hi) << 16);
}

// async 16B global -> LDS DMA (global_load_lds dwordx4)
__device__ __forceinline__ void async_copy16(const float* g, float* l) {
    __builtin_amdgcn_global_load_lds(
        (const __attribute__((address_space(1))) unsigned int*)g,
        (__attribute__((address_space(3))) unsigned int*)l, 16, 0, 0);
}

// ===========================================================================
// Bucketed CSR build (dst-grouped). Per-bucket srcs region is ~32KB
// (L2-resident) so scatter writes don't thrash HBM.
// ===========================================================================
__global__ __launch_bounds__(TPB) void bucket_count(
    const int* __restrict__ dst, int* __restrict__ bucket_cnt, int E, int nbuck)
{
    __shared__ int h[256];
    h[threadIdx.x] = 0;
    __syncthreads();
    int base = blockIdx.x * 1024;
    int lim = min(base + 1024, E);
    for (int i = base + threadIdx.x; i < lim; i += 256)
        atomicAdd(&h[dst[i] >> BSH], 1);
    __syncthreads();
    if (threadIdx.x < nbuck && h[threadIdx.x])
        atomicAdd(&bucket_cnt[threadIdx.x], h[threadIdx.x]);
}

__global__ __launch_bounds__(TPB) void bucket_scan(
    const int* __restrict__ bucket_cnt, int* __restrict__ boff,
    int* __restrict__ bucket_cur, int nbuck, int E)
{
    __shared__ int s[256];
    int t = threadIdx.x;
    int v = (t < nbuck) ? bucket_cnt[t] : 0;
    s[t] = v;
    __syncthreads();
    for (int off = 1; off < 256; off <<= 1) {
        int x = (t >= off) ? s[t - off] : 0;
        __syncthreads();
        s[t] += x;
        __syncthreads();
    }
    int excl = s[t] - v;
    if (t < nbuck) { boff[t] = excl; bucket_cur[t] = excl; }
    if (t == 0) boff[nbuck] = E;
}

__global__ __launch_bounds__(TPB) void partition_edges(
    const int* __restrict__ src, const int* __restrict__ dst,
    int* __restrict__ bucket_cur, int2* __restrict__ pairs, int E, int nbuck)
{
    __shared__ int cnt[256];
    __shared__ int gbase[256];
    int t = threadIdx.x;
    cnt[t] = 0;
    __syncthreads();
    int base = blockIdx.x * 1024;
    int myb[4], myrank[4], mys[4], myd[4];
#pragma unroll
    for (int j = 0; j < 4; ++j) {
        int i = base + j * 256 + t;
        if (i < E) {
            int d = dst[i];
            int b = d >> BSH;
            myb[j] = b; myd[j] = d; mys[j] = src[i];
            myrank[j] = atomicAdd(&cnt[b], 1);
        } else myb[j] = -1;
    }
    __syncthreads();
    if (t < nbuck && cnt[t]) gbase[t] = atomicAdd(&bucket_cur[t], cnt[t]);
    __syncthreads();
#pragma unroll
    for (int j = 0; j < 4; ++j)
        if (myb[j] >= 0)
            pairs[gbase[myb[j]] + myrank[j]] = make_int2(mys[j], myd[j]);
}

// One block per bucket: LDS degree count + scan -> rowptr + degf; local
// scatter of srcs into the bucket's contiguous region.
__global__ __launch_bounds__(TPB) void bucket_build(
    const int2* __restrict__ pairs, const int* __restrict__ boff,
    int* __restrict__ rowptr, int* __restrict__ srcs,
    float* __restrict__ degf, int M, int E)
{
    __shared__ int ldeg[512];
    __shared__ int lsum[256];
    int b = blockIdx.x;
    int t = threadIdx.x;
    int n0 = b << BSH;
    int nn = min(512, M - n0);
    int p0 = boff[b], p1 = boff[b + 1];
    ldeg[t] = 0; ldeg[t + 256] = 0;
    __syncthreads();
    for (int i = p0 + t; i < p1; i += 256)
        atomicAdd(&ldeg[pairs[i].y - n0], 1);
    __syncthreads();
    int a0 = ldeg[2 * t], a1 = ldeg[2 * t + 1];
    lsum[t] = a0 + a1;
    __syncthreads();
    for (int off = 1; off < 256; off <<= 1) {
        int x = (t >= off) ? lsum[t - off] : 0;
        __syncthreads();
        lsum[t] += x;
        __syncthreads();
    }
    int excl = lsum[t] - (a0 + a1);
    ldeg[2 * t]     = p0 + excl;            // becomes scatter cursor
    ldeg[2 * t + 1] = p0 + excl + a0;
    if (2 * t < nn)     { rowptr[n0 + 2 * t]     = p0 + excl;      degf[n0 + 2 * t]     = (float)a0; }
    if (2 * t + 1 < nn) { rowptr[n0 + 2 * t + 1] = p0 + excl + a0; degf[n0 + 2 * t + 1] = (float)a1; }
    if (b == 0 && t == 0) rowptr[M] = E;
    __syncthreads();
    for (int i = p0 + t; i < p1; i += 256) {
        int2 pr = pairs[i];
        int pos = atomicAdd(&ldeg[pr.y - n0], 1);
        srcs[pos] = pr.x;
    }
}

// ===========================================================================
// x -> bf16 convert (once)
// ===========================================================================
__global__ __launch_bounds__(TPB) void cvt_bf16(
    const float* __restrict__ x, unsigned short* __restrict__ xb, int n8)
{
    int i = blockIdx.x * TPB + threadIdx.x;
    if (i >= n8) return;
    const f32x4* p = (const f32x4*)(x + (size_t)i * 8);
    f32x4 v0 = p[0], v1 = p[1];
    uint4 o;
    o.x = packbf(v0.x, v0.y); o.y = packbf(v0.z, v0.w);
    o.z = packbf(v1.x, v1.y); o.w = packbf(v1.z, v1.w);
    *(uint4*)(xb + (size_t)i * 8) = o;
}

// ===========================================================================
// Gather aggregation (bf16 rows, fp32 accumulate): one wave per node.
// 16-lane group g covers feats [li*8,li*8+8) of edge e+g -> one dwordx4
// wave-instruction touches 4 random 256B rows (4 edges in flight; 8 with
// the unroll-2). Cross-group combine via shfl_xor(16/32).
// ===========================================================================
__device__ __forceinline__ void acc8(float* a, uint4 r) {
    a[0] += bflo(r.x); a[1] += bfhi(r.x);
    a[2] += bflo(r.y); a[3] += bfhi(r.y);
    a[4] += bflo(r.z); a[5] += bfhi(r.z);
    a[6] += bflo(r.w); a[7] += bfhi(r.w);
}
__device__ __forceinline__ void acc8m(float* a, uint4 r, float m) {
    a[0] = fmaf(m, bflo(r.x), a[0]); a[1] = fmaf(m, bfhi(r.x), a[1]);
    a[2] = fmaf(m, bflo(r.y), a[2]); a[3] = fmaf(m, bfhi(r.y), a[3]);
    a[4] = fmaf(m, bflo(r.z), a[4]); a[5] = fmaf(m, bfhi(r.z), a[5]);
    a[6] = fmaf(m, bflo(r.w), a[6]); a[7] = fmaf(m, bfhi(r.w), a[7]);
}

__global__ __launch_bounds__(TPB) void gather_bf16(
    const unsigned short* __restrict__ hb, const int* __restrict__ rowptr,
    const int* __restrict__ srcs, float* __restrict__ agg, int M)
{
    int wid = (blockIdx.x * TPB + threadIdx.x) >> 6;
    if (wid >= M) return;
    int lane = threadIdx.x & 63;
    int grp  = lane >> 4;
    int li   = lane & 15;
    int start = rowptr[wid], end = rowptr[wid + 1];

    float a0[8] = {0, 0, 0, 0, 0, 0, 0, 0};
    float a1[8] = {0, 0, 0, 0, 0, 0, 0, 0};
    int e = start;
    for (; e + 7 < end; e += 8) {
        int s0 = srcs[e + grp];
        int s1 = srcs[e + 4 + grp];
        uint4 r0 = *(const uint4*)(hb + (size_t)s0 * NF + li * 8);
        uint4 r1 = *(const uint4*)(hb + (size_t)s1 * NF + li * 8);
        acc8(a0, r0);
        acc8(a1, r1);
    }
    for (; e < end; e += 4) {
        int idx = e + grp;
        int s = srcs[min(idx, end - 1)];
        uint4 r = *(const uint4*)(hb + (size_t)s * NF + li * 8);
        float m = (idx < end) ? 1.0f : 0.0f;
        acc8m(a0, r, m);
    }
#pragma unroll
    for (int j = 0; j < 8; ++j) a0[j] += a1[j];
#pragma unroll
    for (int j = 0; j < 8; ++j) a0[j] += __shfl_xor(a0[j], 16);
#pragma unroll
    for (int j = 0; j < 8; ++j) a0[j] += __shfl_xor(a0[j], 32);
    if (lane < 16) {
        float* o = agg + (size_t)wid * NF + li * 8;
        *(f32x4*)o       = (f32x4){a0[0], a0[1], a0[2], a0[3]};
        *(f32x4*)(o + 4) = (f32x4){a0[4], a0[5], a0[6], a0[7]};
    }
}

// ===========================================================================
// Layer-1 W prep: transpose + concat + split bf16 hi/lo (no norm).
// ===========================================================================
__global__ __launch_bounds__(256) void wsplit_kernel(
    const float* __restrict__ Wr, const float* __restrict__ Wo,
    short* __restrict__ hi, short* __restrict__ lo)
{
    int n = blockIdx.x;      // 0..127
    int k = threadIdx.x;     // 0..255
    float v = (k < NF) ? Wr[k * NF + n] : Wo[(k - NF) * NF + n];
    short h = f2bf(v);
    hi[n * 256 + k] = h;
    lo[n * 256 + k] = f2bf(v - bf2f(h));
}

// ===========================================================================
// Fold BN affine (a,c) of the previous layer into this layer's weights.
// ===========================================================================
__global__ __launch_bounds__(256) void fold_kernel(
    const float* __restrict__ a, const float* __restrict__ c,
    const float* __restrict__ Wr, const float* __restrict__ Wo,
    const float* __restrict__ b,
    short* __restrict__ hi, short* __restrict__ lo,
    float* __restrict__ bias2, float* __restrict__ dvec)
{
    __shared__ float red[256];
    int n = blockIdx.x;
    int k = threadIdx.x;
    float w, contrib;
    if (k < NF) { w = Wr[k * NF + n];          contrib = c[k] * w;       w *= a[k]; }
    else        { int kk = k - NF; w = Wo[kk * NF + n]; contrib = c[kk] * w; w *= a[kk]; }
    short h = f2bf(w);
    hi[n * 256 + k] = h;
    lo[n * 256 + k] = f2bf(w - bf2f(h));
    red[k] = contrib;
    __syncthreads();
    for (int off = 64; off >= 1; off >>= 1) {
        if ((k & 127) < off) red[k] += red[k + off];
        __syncthreads();
    }
    if (k == 0)   dvec[n]  = red[0];
    if (k == 128) bias2[n] = b[n] + red[128];
}

// ===========================================================================
// MFMA dual GEMM v3:
//   C = S @ Wt_agg^T + h_bf16 @ Wt_root^T + bias (+deg*dvec) (+ReLU) (+stats)
// Root-path chunks first: A frags loaded DIRECT from bf16 rows (no convert,
// 2-term W hi/lo). Agg chunks: fp32 LDS-staged (global_load_lds, 16B XOR
// swizzle), split-bf16 3-term. C written bf16 in-place over Ax's stripe
// (this block reads only its own 128-row stripe of Ax).
// ===========================================================================
template<bool RELU, bool NORM>
__global__ __launch_bounds__(TPB) void gemm_mfma(
    const float* __restrict__ Aagg, const unsigned short* Ax,   // Ax may alias C
    const short* __restrict__ wt_hi, const short* __restrict__ wt_lo,
    const float* __restrict__ bias, const float* __restrict__ dvec,
    const float* __restrict__ degf, unsigned short* C,
    float* __restrict__ gsum, float* __restrict__ gsq, int M)
{
    __shared__ float sA[4096];         // 16 KB chunk buffer; reused for stats

    const int tid  = threadIdx.x;
    const int wid  = tid >> 6;
    const int lane = tid & 63;
    const int lg   = lane >> 4;        // quad 0..3
    const int ln   = lane & 15;
    const int m0   = blockIdx.x * 128;
    const int rowbase = m0 + wid * 32;

    f32x4 acc[2][8];
#pragma unroll
    for (int i = 0; i < 2; ++i)
#pragma unroll
        for (int j = 0; j < 8; ++j) acc[i][j] = (f32x4){0.f, 0.f, 0.f, 0.f};

    // ---- root-path chunks (bf16 direct, K = 128..256 in concat space) ----
#pragma unroll
    for (int kc = 0; kc < 4; ++kc) {
        const int k0 = NF + kc * 32;
        bf16x8 af[2];
#pragma unroll
        for (int mt = 0; mt < 2; ++mt) {
            int row = min(rowbase + mt * 16 + ln, M - 1);
            af[mt] = *(const bf16x8*)(Ax + (size_t)row * NF + kc * 32 + lg * 8);
        }
#pragma unroll
        for (int nt = 0; nt < 8; ++nt) {
            const size_t wof = (size_t)(nt * 16 + ln) * 256 + k0 + lg * 8;
            bf16x8 bhi = *(const bf16x8*)(wt_hi + wof);
            bf16x8 blo = *(const bf16x8*)(wt_lo + wof);
#pragma unroll
            for (int mt = 0; mt < 2; ++mt) {
                acc[mt][nt] = __builtin_amdgcn_mfma_f32_16x16x32_bf16(af[mt], bhi, acc[mt][nt], 0, 0, 0);
                acc[mt][nt] = __builtin_amdgcn_mfma_f32_16x16x32_bf16(af[mt], blo, acc[mt][nt], 0, 0, 0);
            }
        }
    }

    // ---- agg chunks (fp32 staged, split 3-term, K = 0..128) ----
#pragma unroll
    for (int kc = 0; kc < 4; ++kc) {
        const int kbase = kc * 32;

        __syncthreads();                // prior chunk fully consumed
#pragma unroll
        for (int is = 0; is < 4; ++is) {
            int seg  = is * 256 + tid;              // 0..1023
            int row  = seg >> 3;                    // 0..127 (local)
            int kgs  = seg & 7;                     // LDS 16B slot in row
            int kgg  = kgs ^ (row & 7);             // global 16B slot (swizzle)
            int rowg = min(m0 + row, M - 1);
            async_copy16(Aagg + (size_t)rowg * NF + kbase + kgg * 4, sA + seg * 4);
        }
        __syncthreads();

        bf16x8 ahi[2], alo[2];
#pragma unroll
        for (int mt = 0; mt < 2; ++mt) {
            int lrow = wid * 32 + mt * 16 + ln;
            int r7 = lrow & 7;
            f32x4 p0 = *(const f32x4*)(sA + lrow * 32 + (((lg * 2 + 0) ^ r7) << 2));
            f32x4 p1 = *(const f32x4*)(sA + lrow * 32 + (((lg * 2 + 1) ^ r7) << 2));
            float vv[8] = {p0.x, p0.y, p0.z, p0.w, p1.x, p1.y, p1.z, p1.w};
#pragma unroll
            for (int j = 0; j < 8; ++j) {
                short h = f2bf(vv[j]);
                ahi[mt][j] = h;
                alo[mt][j] = f2bf(vv[j] - bf2f(h));
            }
        }
#pragma unroll
        for (int nt = 0; nt < 8; ++nt) {
            const size_t wof = (size_t)(nt * 16 + ln) * 256 + kbase + lg * 8;
            bf16x8 bhi = *(const bf16x8*)(wt_hi + wof);
            bf16x8 blo = *(const bf16x8*)(wt_lo + wof);
#pragma unroll
            for (int mt = 0; mt < 2; ++mt) {
                acc[mt][nt] = __builtin_amdgcn_mfma_f32_16x16x32_bf16(ahi[mt], bhi, acc[mt][nt], 0, 0, 0);
                acc[mt][nt] = __builtin_amdgcn_mfma_f32_16x16x32_bf16(alo[mt], bhi, acc[mt][nt], 0, 0, 0);
                acc[mt][nt] = __builtin_amdgcn_mfma_f32_16x16x32_bf16(ahi[mt], blo, acc[mt][nt], 0, 0, 0);
            }
        }
    }

    // ---- epilogue: bias (+deg*dvec) (+ReLU), bf16 store, fused BN stats ----
    float B_[8], D_[8];
#pragma unroll
    for (int nt = 0; nt < 8; ++nt) {
        B_[nt] = bias[nt * 16 + ln];
        D_[nt] = NORM ? dvec[nt * 16 + ln] : 0.f;
    }
    float s8[8], q8[8];
#pragma unroll
    for (int nt = 0; nt < 8; ++nt) { s8[nt] = 0.f; q8[nt] = 0.f; }

#pragma unroll
    for (int mt = 0; mt < 2; ++mt) {
#pragma unroll
        for (int r = 0; r < 4; ++r) {
            int row = rowbase + mt * 16 + lg * 4 + r;
            if (row < M) {
                float dg = NORM ? degf[row] : 0.f;
#pragma unroll
                for (int nt = 0; nt < 8; ++nt) {
                    float v = acc[mt][nt][r] + B_[nt];
                    if (NORM) v += dg * D_[nt];
                    if (RELU) v = fmaxf(v, 0.f);
                    C[(size_t)row * NF + nt * 16 + ln] = (unsigned short)f2bf(v);
                    s8[nt] += v;
                    q8[nt] += v * v;
                }
            }
        }
    }

    __syncthreads();                   // done with sA as A-buffer
    float* ssum = sA;                  // [16][128]
    float* ssq  = sA + 2048;
    const int rg = wid * 4 + lg;
#pragma unroll
    for (int nt = 0; nt < 8; ++nt) {
        ssum[rg * NF + nt * 16 + ln] = s8[nt];
        ssq [rg * NF + nt * 16 + ln] = q8[nt];
    }
    __syncthreads();
    if (tid < NF) {
        float s = 0.f, q = 0.f;
#pragma unroll
        for (int g = 0; g < 16; ++g) { s += ssum[g * NF + tid]; q += ssq[g * NF + tid]; }
        atomAddF(&gsum[tid], s);
        atomAddF(&gsq[tid], q);
    }
}

// Fold BN into affine: a = gamma*rsqrt(var+eps), c = beta - mean*a
__global__ __launch_bounds__(128) void bn_finalize(
    const float* __restrict__ gsum, const float* __restrict__ gsq,
    const float* __restrict__ gamma, const float* __restrict__ beta,
    float* __restrict__ a, float* __restrict__ c, int M)
{
    int k = threadIdx.x;
    float invM = 1.0f / (float)M;
    float mean = gsum[k] * invM;
    float var  = fmaxf(gsq[k] * invM - mean * mean, 0.f);
    float s    = gamma[k] / sqrtf(var + BN_EPS_C);
    a[k] = s;
    c[k] = beta[k] - mean * s;
}

// ---------------------------------------------------------------------------
// Pooling (bf16 input): batch is SORTED -> run-length accumulate.
// ---------------------------------------------------------------------------
__global__ __launch_bounds__(TPB) void pool_kernel(
    const unsigned short* __restrict__ h, const int* __restrict__ batch,
    float* __restrict__ pooled, float* __restrict__ counts, int M)
{
    int base = blockIdx.x * 128;
    int col  = threadIdx.x & 127;
    int half = threadIdx.x >> 7;
    int end  = min(base + 128, M);
    float acc = 0.f; int cnt = 0; int gcur = -1;
    for (int n = base + half; n < end; n += 2) {
        int g = batch[n];
        if (g != gcur) {
            if (gcur >= 0) {
                atomAddF(&pooled[(size_t)gcur * NF + col], acc);
                if (col == 0) atomAddF(&counts[gcur], (float)cnt);
            }
            acc = 0.f; cnt = 0; gcur = g;
        }
        acc += bf2f((short)h[(size_t)n * NF + col]);
        cnt += 1;
    }
    if (gcur >= 0) {
        atomAddF(&pooled[(size_t)gcur * NF + col], acc);
        if (col == 0) atomAddF(&counts[gcur], (float)cnt);
    }
}

__global__ __launch_bounds__(TPB) void final_kernel(
    const float* __restrict__ pooled, const float* __restrict__ counts,
    const float* __restrict__ a3, const float* __restrict__ c3,
    const float* __restrict__ Wlin, const float* __restrict__ blin,
    float* __restrict__ out, int G)
{
    int g = threadIdx.x;
    if (g >= G) return;
    float cntRaw = counts[g];
    float inv = 1.0f / fmaxf(cntRaw, 1.0f);
    float nonEmpty = cntRaw > 0.5f ? 1.0f : 0.0f;
    float acc0 = 0.f, acc1 = 0.f;
    for (int k = 0; k < NF; ++k) {
        float v = (a3[k] * pooled[(size_t)g * NF + k] * inv + c3[k]) * nonEmpty;
        acc0 += v * Wlin[k * 2 + 0];
        acc1 += v * Wlin[k * 2 + 1];
    }
    out[g * 2 + 0] = acc0 + blin[0];
    out[g * 2 + 1] = acc1 + blin[1];
}

// ---------------------------------------------------------------------------
extern "C" void kernel_launch(void* const* d_in, const int* in_sizes, int n_in,
                              void* d_out, int out_size, void* d_ws, size_t ws_size,
                              hipStream_t stream)
{
    const float* x     = (const float*)d_in[0];
    const int*   eidx  = (const int*)d_in[1];
    const int*   batch = (const int*)d_in[2];
    const float* W1r = (const float*)d_in[3],  *b1 = (const float*)d_in[4];
    const float* W1o = (const float*)d_in[5],  *g1 = (const float*)d_in[6],  *be1 = (const float*)d_in[7];
    const float* W2r = (const float*)d_in[8],  *b2 = (const float*)d_in[9];
    const float* W2o = (const float*)d_in[10], *g2 = (const float*)d_in[11], *be2 = (const float*)d_in[12];
    const float* W3r = (const float*)d_in[13], *b3 = (const float*)d_in[14];
    const float* W3o = (const float*)d_in[15], *g3 = (const float*)d_in[16], *be3 = (const float*)d_in[17];
    const float* Wlin = (const float*)d_in[18], *blin = (const float*)d_in[19];
    float* out = (float*)d_out;

    const int M = in_sizes[0] / NF;        // 100000 nodes
    const int E = in_sizes[1] / 2;         // 1.6M edges
    const int G = out_size / 2;            // 256 graphs
    const int* src = eidx;
    const int* dst = eidx + E;
    const int nbuck = (M + 511) >> BSH;

    const size_t NODEF = (size_t)M * NF;

    // ---- workspace layout ----
    float* agg = (float*)d_ws;                     // NODEF fp32 (51.2 MB)
    unsigned short* xb = (unsigned short*)(agg + NODEF);  // NODEF bf16 (25.6 MB)
    unsigned short* hb = xb + NODEF;               // NODEF bf16 (25.6 MB)
    float* zf   = (float*)(hb + NODEF);            // zeroed float zone
    float* gsum1 = zf;        float* gsq1 = zf + 128;
    float* gsum2 = zf + 256;  float* gsq2 = zf + 384;
    float* gsum3 = zf + 512;  float* gsq3 = zf + 640;
    float* counts = zf + 768;                      // G
    float* pooled = counts + G;                    // G*NF
    int*   zi   = (int*)(pooled + (size_t)G * NF); // zeroed int zone (1024)
    int* bucket_cnt = zi;                          // 256
    int* bucket_cur = zi + 256;                    // 256
    int* boff       = zi + 512;                    // nbuck+1 (<=257)
    int* ziEnd      = zi + 1024;
    float* ac = (float*)ziEnd;                     // a/c per layer + fold outs
    float* a1 = ac;       float* c1 = ac + 128;
    float* a2 = ac + 256; float* c2 = ac + 384;
    float* a3 = ac + 512; float* c3 = ac + 640;
    float* bias2_2 = ac + 768;  float* dvec2 = ac + 896;
    float* bias2_3 = ac + 1024; float* dvec3 = ac + 1152;
    int* rowptr = (int*)(ac + 1280);               // M+1
    int* srcs   = rowptr + (M + 1);                // E
    float* degf = (float*)(srcs + E);              // M
    uintptr_t pp = ((uintptr_t)(degf + M) + 15) & ~(uintptr_t)15;
    int2* pairs = (int2*)pp;                       // E (CSR build only)
    // wt buffers UNION with pairs (pairs dead before wsplit/fold run)
    short* wt1_hi = (short*)pp;                    // each plane 128*256
    short* wt1_lo = wt1_hi + 32768;
    short* wt2_hi = wt1_hi + 65536;
    short* wt2_lo = wt1_hi + 98304;
    short* wt3_hi = wt1_hi + 131072;
    short* wt3_lo = wt1_hi + 163840;

    const int gridE1024    = (E + 1023) / 1024;
    const int gatherBlocks = (int)(((size_t)M * 64 + TPB - 1) / TPB);
    const int gemmBlocks   = (M + 127) / 128;
    const int poolBlocks   = (M + 127) / 128;
    const int cvtBlocks    = (int)((NODEF / 8 + TPB - 1) / TPB);

    // single memset: float zone + int zone
    size_t zbytes = (char*)ziEnd - (char*)zf;
    hipMemsetAsync(zf, 0, zbytes, stream);

    // ---- bucketed reverse-CSR build (dst-grouped), reused by all 3 layers
    bucket_count   <<<gridE1024, TPB, 0, stream>>>(dst, bucket_cnt, E, nbuck);
    bucket_scan    <<<1, TPB, 0, stream>>>(bucket_cnt, boff, bucket_cur, nbuck, E);
    partition_edges<<<gridE1024, TPB, 0, stream>>>(src, dst, bucket_cur, pairs, E, nbuck);
    bucket_build   <<<nbuck, TPB, 0, stream>>>(pairs, boff, rowptr, srcs, degf, M, E);

    // ---- x -> bf16 (after CSR: runs while nothing depends on it yet)
    cvt_bf16<<<cvtBlocks, TPB, 0, stream>>>(x, xb, (int)(NODEF / 8));

    // ---- layer 1 (no incoming norm)
    wsplit_kernel<<<128, 256, 0, stream>>>(W1r, W1o, wt1_hi, wt1_lo);
    gather_bf16<<<gatherBlocks, TPB, 0, stream>>>(xb, rowptr, srcs, agg, M);
    gemm_mfma<true, false><<<gemmBlocks, TPB, 0, stream>>>(
        agg, xb, wt1_hi, wt1_lo, b1, nullptr, nullptr, hb, gsum1, gsq1, M);
    bn_finalize<<<1, 128, 0, stream>>>(gsum1, gsq1, g1, be1, a1, c1, M);

    // ---- layer 2 (norm1 folded into weights)
    fold_kernel<<<128, 256, 0, stream>>>(a1, c1, W2r, W2o, b2, wt2_hi, wt2_lo, bias2_2, dvec2);
    gather_bf16<<<gatherBlocks, TPB, 0, stream>>>(hb, rowptr, srcs, agg, M);
    gemm_mfma<true, true><<<gemmBlocks, TPB, 0, stream>>>(
        agg, hb, wt2_hi, wt2_lo, bias2_2, dvec2, degf, hb, gsum2, gsq2, M);
    bn_finalize<<<1, 128, 0, stream>>>(gsum2, gsq2, g2, be2, a2, c2, M);

    // ---- layer 3 (no ReLU; norm2 folded into weights)
    fold_kernel<<<128, 256, 0, stream>>>(a2, c2, W3r, W3o, b3, wt3_hi, wt3_lo, bias2_3, dvec3);
    gather_bf16<<<gatherBlocks, TPB, 0, stream>>>(hb, rowptr, srcs, agg, M);
    gemm_mfma<false, true><<<gemmBlocks, TPB, 0, stream>>>(
        agg, hb, wt3_hi, wt3_lo, bias2_3, dvec3, degf, hb, gsum3, gsq3, M);
    bn_finalize<<<1, 128, 0, stream>>>(gsum3, gsq3, g3, be3, a3, c3, M);

    // ---- pool + classify (norm3 applied on pooled means)
    pool_kernel<<<poolBlocks, TPB, 0, stream>>>(hb, batch, pooled, counts, M);
    final_kernel<<<1, TPB, 0, stream>>>(pooled, counts, a3, c3, Wlin, blin, out, G);
}

// Round 7
// 689.779 us; speedup vs baseline: 6.9872x; 1.0186x over previous
//
#include <hip/hip_runtime.h>
#include <math.h>
#include <stdint.h>

#define TPB 256
#define NF 128          // feature width (all layers)
#define BN_EPS_C 1e-5f
#define BSH 9           // bucket shift: 512 nodes per bucket
#define PE_EPB 4096     // edges per block in count/partition

typedef __attribute__((ext_vector_type(8))) short bf16x8;   // 8 bf16 (4 VGPRs)
typedef __attribute__((ext_vector_type(4))) float f32x4;    // 4 fp32

// ---------------------------------------------------------------------------
__device__ __forceinline__ void atomAddF(float* p, float v) {
    unsafeAtomicAdd(p, v);
}

// fp32 <-> bf16 (RNE), bit-level
__device__ __forceinline__ short f2bf(float f) {
    unsigned u = __float_as_uint(f);
    unsigned r = (u + 0x7FFFu + ((u >> 16) & 1u)) >> 16;
    return (short)r;
}
__device__ __forceinline__ float bf2f(short b) {
    return __uint_as_float(((unsigned)(unsigned short)b) << 16);
}
__device__ __forceinline__ float bflo(unsigned u) { return __uint_as_float(u << 16); }
__device__ __forceinline__ float bfhi(unsigned u) { return __uint_as_float(u & 0xffff0000u); }
__device__ __forceinline__ unsigned packbf(float lo, float hi) {
    return (unsigned)(unsigned short)f2bf(lo) | ((unsigned)(unsigned short)f2bf(hi) << 16);
}

// ===========================================================================
// Bucketed CSR build (dst-grouped). Per-bucket srcs region is ~32KB
// (L2-resident) so scatter writes don't thrash HBM.
// ===========================================================================
__global__ __launch_bounds__(TPB) void bucket_count(
    const int* __restrict__ dst, int* __restrict__ bucket_cnt, int E, int nbuck)
{
    __shared__ int h[256];
    h[threadIdx.x] = 0;
    __syncthreads();
    int base = blockIdx.x * PE_EPB;
    int lim = min(base + PE_EPB, E);
    for (int i = base + threadIdx.x; i < lim; i += 256)
        atomicAdd(&h[dst[i] >> BSH], 1);
    __syncthreads();
    if (threadIdx.x < nbuck && h[threadIdx.x])
        atomicAdd(&bucket_cnt[threadIdx.x], h[threadIdx.x]);
}

__global__ __launch_bounds__(TPB) void bucket_scan(
    const int* __restrict__ bucket_cnt, int* __restrict__ boff,
    int* __restrict__ bucket_cur, int nbuck, int E)
{
    __shared__ int s[256];
    int t = threadIdx.x;
    int v = (t < nbuck) ? bucket_cnt[t] : 0;
    s[t] = v;
    __syncthreads();
    for (int off = 1; off < 256; off <<= 1) {
        int x = (t >= off) ? s[t - off] : 0;
        __syncthreads();
        s[t] += x;
        __syncthreads();
    }
    int excl = s[t] - v;
    if (t < nbuck) { boff[t] = excl; bucket_cur[t] = excl; }
    if (t == 0) boff[nbuck] = E;
}

// Partition edges into bucket-ordered (src,dst) pairs; 4096 edges/block ->
// ~21 contiguous pairs per bucket-stream per block (less write amplification).
__global__ __launch_bounds__(TPB) void partition_edges(
    const int* __restrict__ src, const int* __restrict__ dst,
    int* __restrict__ bucket_cur, int2* __restrict__ pairs, int E, int nbuck)
{
    __shared__ int cnt[256];
    __shared__ int gbase[256];
    int t = threadIdx.x;
    cnt[t] = 0;
    __syncthreads();
    int base = blockIdx.x * PE_EPB;
    int myb[16], myrank[16], mys[16], myd[16];
#pragma unroll
    for (int j = 0; j < 16; ++j) {
        int i = base + j * 256 + t;
        if (i < E) {
            int d = dst[i];
            int b = d >> BSH;
            myb[j] = b; myd[j] = d; mys[j] = src[i];
            myrank[j] = atomicAdd(&cnt[b], 1);
        } else myb[j] = -1;
    }
    __syncthreads();
    if (t < nbuck && cnt[t]) gbase[t] = atomicAdd(&bucket_cur[t], cnt[t]);
    __syncthreads();
#pragma unroll
    for (int j = 0; j < 16; ++j)
        if (myb[j] >= 0)
            pairs[gbase[myb[j]] + myrank[j]] = make_int2(mys[j], myd[j]);
}

// One block per bucket: LDS degree count + scan -> rowptr + degf; local
// scatter of srcs into the bucket's contiguous region.
__global__ __launch_bounds__(TPB) void bucket_build(
    const int2* __restrict__ pairs, const int* __restrict__ boff,
    int* __restrict__ rowptr, int* __restrict__ srcs,
    float* __restrict__ degf, int M, int E)
{
    __shared__ int ldeg[512];
    __shared__ int lsum[256];
    int b = blockIdx.x;
    int t = threadIdx.x;
    int n0 = b << BSH;
    int nn = min(512, M - n0);
    int p0 = boff[b], p1 = boff[b + 1];
    ldeg[t] = 0; ldeg[t + 256] = 0;
    __syncthreads();
    for (int i = p0 + t; i < p1; i += 256)
        atomicAdd(&ldeg[pairs[i].y - n0], 1);
    __syncthreads();
    int a0 = ldeg[2 * t], a1 = ldeg[2 * t + 1];
    lsum[t] = a0 + a1;
    __syncthreads();
    for (int off = 1; off < 256; off <<= 1) {
        int x = (t >= off) ? lsum[t - off] : 0;
        __syncthreads();
        lsum[t] += x;
        __syncthreads();
    }
    int excl = lsum[t] - (a0 + a1);
    ldeg[2 * t]     = p0 + excl;            // becomes scatter cursor
    ldeg[2 * t + 1] = p0 + excl + a0;
    if (2 * t < nn)     { rowptr[n0 + 2 * t]     = p0 + excl;      degf[n0 + 2 * t]     = (float)a0; }
    if (2 * t + 1 < nn) { rowptr[n0 + 2 * t + 1] = p0 + excl + a0; degf[n0 + 2 * t + 1] = (float)a1; }
    if (b == 0 && t == 0) rowptr[M] = E;
    __syncthreads();
    for (int i = p0 + t; i < p1; i += 256) {
        int2 pr = pairs[i];
        int pos = atomicAdd(&ldeg[pr.y - n0], 1);
        srcs[pos] = pr.x;
    }
}

// ===========================================================================
// x -> bf16 convert (once)
// ===========================================================================
__global__ __launch_bounds__(TPB) void cvt_bf16(
    const float* __restrict__ x, unsigned short* __restrict__ xb, int n8)
{
    int i = blockIdx.x * TPB + threadIdx.x;
    if (i >= n8) return;
    const f32x4* p = (const f32x4*)(x + (size_t)i * 8);
    f32x4 v0 = p[0], v1 = p[1];
    uint4 o;
    o.x = packbf(v0.x, v0.y); o.y = packbf(v0.z, v0.w);
    o.z = packbf(v1.x, v1.y); o.w = packbf(v1.z, v1.w);
    *(uint4*)(xb + (size_t)i * 8) = o;
}

// ===========================================================================
// Gather aggregation (bf16 rows, fp32 accumulate), output SPLIT into two
// bf16 planes (hi = RNE(v), lo = RNE(v-hi)) so the GEMM can consume A
// fragments directly with zero conversion and no LDS staging.
// One wave per node; 16-lane group g covers feats [li*8,li*8+8) of edge e+g.
// ===========================================================================
__device__ __forceinline__ void acc8(float* a, uint4 r) {
    a[0] += bflo(r.x); a[1] += bfhi(r.x);
    a[2] += bflo(r.y); a[3] += bfhi(r.y);
    a[4] += bflo(r.z); a[5] += bfhi(r.z);
    a[6] += bflo(r.w); a[7] += bfhi(r.w);
}
__device__ __forceinline__ void acc8m(float* a, uint4 r, float m) {
    a[0] = fmaf(m, bflo(r.x), a[0]); a[1] = fmaf(m, bfhi(r.x), a[1]);
    a[2] = fmaf(m, bflo(r.y), a[2]); a[3] = fmaf(m, bfhi(r.y), a[3]);
    a[4] = fmaf(m, bflo(r.z), a[4]); a[5] = fmaf(m, bfhi(r.z), a[5]);
    a[6] = fmaf(m, bflo(r.w), a[6]); a[7] = fmaf(m, bfhi(r.w), a[7]);
}

__global__ __launch_bounds__(TPB) void gather_bf16(
    const unsigned short* __restrict__ hb, const int* __restrict__ rowptr,
    const int* __restrict__ srcs,
    unsigned short* __restrict__ agg_hi, unsigned short* __restrict__ agg_lo, int M)
{
    int wid = (blockIdx.x * TPB + threadIdx.x) >> 6;
    if (wid >= M) return;
    int lane = threadIdx.x & 63;
    int grp  = lane >> 4;
    int li   = lane & 15;
    int start = rowptr[wid], end = rowptr[wid + 1];

    float a0[8] = {0, 0, 0, 0, 0, 0, 0, 0};
    float a1[8] = {0, 0, 0, 0, 0, 0, 0, 0};
    int e = start;
    for (; e + 7 < end; e += 8) {
        int s0 = srcs[e + grp];
        int s1 = srcs[e + 4 + grp];
        uint4 r0 = *(const uint4*)(hb + (size_t)s0 * NF + li * 8);
        uint4 r1 = *(const uint4*)(hb + (size_t)s1 * NF + li * 8);
        acc8(a0, r0);
        acc8(a1, r1);
    }
    for (; e < end; e += 4) {
        int idx = e + grp;
        int s = srcs[min(idx, end - 1)];
        uint4 r = *(const uint4*)(hb + (size_t)s * NF + li * 8);
        float m = (idx < end) ? 1.0f : 0.0f;
        acc8m(a0, r, m);
    }
#pragma unroll
    for (int j = 0; j < 8; ++j) a0[j] += a1[j];
#pragma unroll
    for (int j = 0; j < 8; ++j) a0[j] += __shfl_xor(a0[j], 16);
#pragma unroll
    for (int j = 0; j < 8; ++j) a0[j] += __shfl_xor(a0[j], 32);
    if (lane < 16) {
        float h[8], l[8];
#pragma unroll
        for (int j = 0; j < 8; ++j) {
            h[j] = bf2f(f2bf(a0[j]));
            l[j] = a0[j] - h[j];
        }
        uint4 oh, ol;
        oh.x = packbf(h[0], h[1]); oh.y = packbf(h[2], h[3]);
        oh.z = packbf(h[4], h[5]); oh.w = packbf(h[6], h[7]);
        ol.x = packbf(l[0], l[1]); ol.y = packbf(l[2], l[3]);
        ol.z = packbf(l[4], l[5]); ol.w = packbf(l[6], l[7]);
        *(uint4*)(agg_hi + (size_t)wid * NF + li * 8) = oh;
        *(uint4*)(agg_lo + (size_t)wid * NF + li * 8) = ol;
    }
}

// ===========================================================================
// Layer-1 W prep: transpose + concat + split bf16 hi/lo (no norm).
// ===========================================================================
__global__ __launch_bounds__(256) void wsplit_kernel(
    const float* __restrict__ Wr, const float* __restrict__ Wo,
    short* __restrict__ hi, short* __restrict__ lo)
{
    int n = blockIdx.x;      // 0..127
    int k = threadIdx.x;     // 0..255
    float v = (k < NF) ? Wr[k * NF + n] : Wo[(k - NF) * NF + n];
    short h = f2bf(v);
    hi[n * 256 + k] = h;
    lo[n * 256 + k] = f2bf(v - bf2f(h));
}

// ===========================================================================
// Fold BN affine (a,c) of the previous layer into this layer's weights.
// ===========================================================================
__global__ __launch_bounds__(256) void fold_kernel(
    const float* __restrict__ a, const float* __restrict__ c,
    const float* __restrict__ Wr, const float* __restrict__ Wo,
    const float* __restrict__ b,
    short* __restrict__ hi, short* __restrict__ lo,
    float* __restrict__ bias2, float* __restrict__ dvec)
{
    __shared__ float red[256];
    int n = blockIdx.x;
    int k = threadIdx.x;
    float w, contrib;
    if (k < NF) { w = Wr[k * NF + n];          contrib = c[k] * w;       w *= a[k]; }
    else        { int kk = k - NF; w = Wo[kk * NF + n]; contrib = c[kk] * w; w *= a[kk]; }
    short h = f2bf(w);
    hi[n * 256 + k] = h;
    lo[n * 256 + k] = f2bf(w - bf2f(h));
    red[k] = contrib;
    __syncthreads();
    for (int off = 64; off >= 1; off >>= 1) {
        if ((k & 127) < off) red[k] += red[k + off];
        __syncthreads();
    }
    if (k == 0)   dvec[n]  = red[0];
    if (k == 128) bias2[n] = b[n] + red[128];
}

// ===========================================================================
// MFMA dual GEMM v4 — barrier-free direct-load:
//   C = Shi/Slo @ Wt_agg^T (3-term) + h_bf16 @ Wt_root^T (2-term)
//       + bias (+deg*dvec) (+ReLU) (+fused BN stats)
// All A fragments are per-lane bf16x8 global loads (no LDS staging, no
// f2bf chains, no __syncthreads in the K-loop) -> waves slip freely and
// the compiler pipelines loads across the fully-unrolled K-loop.
// C written bf16 in-place over Ax's stripe (block-private 128-row stripe).
// ===========================================================================
template<bool RELU, bool NORM>
__global__ __launch_bounds__(TPB) void gemm_mfma(
    const unsigned short* __restrict__ Ahi, const unsigned short* __restrict__ Alo,
    const unsigned short* Ax,                                  // may alias C
    const short* __restrict__ wt_hi, const short* __restrict__ wt_lo,
    const float* __restrict__ bias, const float* __restrict__ dvec,
    const float* __restrict__ degf, unsigned short* C,
    float* __restrict__ gsum, float* __restrict__ gsq, int M)
{
    __shared__ float sred[4096];       // stats scratch only (16 KB)

    const int tid  = threadIdx.x;
    const int wid  = tid >> 6;
    const int lane = tid & 63;
    const int lg   = lane >> 4;        // quad 0..3
    const int ln   = lane & 15;
    const int rowbase = blockIdx.x * 128 + wid * 32;

    f32x4 acc[2][8];
#pragma unroll
    for (int i = 0; i < 2; ++i)
#pragma unroll
        for (int j = 0; j < 8; ++j) acc[i][j] = (f32x4){0.f, 0.f, 0.f, 0.f};

    int arow[2];
#pragma unroll
    for (int mt = 0; mt < 2; ++mt)
        arow[mt] = min(rowbase + mt * 16 + ln, M - 1);

    // ---- agg-path chunks (3-term split, concat-K 0..128) ----
#pragma unroll
    for (int kc = 0; kc < 4; ++kc) {
        const int kf = kc * 32 + lg * 8;            // feat offset of this frag
        bf16x8 ahi[2], alo[2];
#pragma unroll
        for (int mt = 0; mt < 2; ++mt) {
            ahi[mt] = *(const bf16x8*)(Ahi + (size_t)arow[mt] * NF + kf);
            alo[mt] = *(const bf16x8*)(Alo + (size_t)arow[mt] * NF + kf);
        }
#pragma unroll
        for (int nt = 0; nt < 8; ++nt) {
            const size_t wof = (size_t)(nt * 16 + ln) * 256 + kc * 32 + lg * 8;
            bf16x8 bhi = *(const bf16x8*)(wt_hi + wof);
            bf16x8 blo = *(const bf16x8*)(wt_lo + wof);
#pragma unroll
            for (int mt = 0; mt < 2; ++mt) {
                acc[mt][nt] = __builtin_amdgcn_mfma_f32_16x16x32_bf16(ahi[mt], bhi, acc[mt][nt], 0, 0, 0);
                acc[mt][nt] = __builtin_amdgcn_mfma_f32_16x16x32_bf16(alo[mt], bhi, acc[mt][nt], 0, 0, 0);
                acc[mt][nt] = __builtin_amdgcn_mfma_f32_16x16x32_bf16(ahi[mt], blo, acc[mt][nt], 0, 0, 0);
            }
        }
    }

    // ---- root-path chunks (2-term, concat-K 128..256) ----
#pragma unroll
    for (int kc = 0; kc < 4; ++kc) {
        const int kf = kc * 32 + lg * 8;
        bf16x8 af[2];
#pragma unroll
        for (int mt = 0; mt < 2; ++mt)
            af[mt] = *(const bf16x8*)(Ax + (size_t)arow[mt] * NF + kf);
#pragma unroll
        for (int nt = 0; nt < 8; ++nt) {
            const size_t wof = (size_t)(nt * 16 + ln) * 256 + NF + kc * 32 + lg * 8;
            bf16x8 bhi = *(const bf16x8*)(wt_hi + wof);
            bf16x8 blo = *(const bf16x8*)(wt_lo + wof);
#pragma unroll
            for (int mt = 0; mt < 2; ++mt) {
                acc[mt][nt] = __builtin_amdgcn_mfma_f32_16x16x32_bf16(af[mt], bhi, acc[mt][nt], 0, 0, 0);
                acc[mt][nt] = __builtin_amdgcn_mfma_f32_16x16x32_bf16(af[mt], blo, acc[mt][nt], 0, 0, 0);
            }
        }
    }

    // ---- epilogue: bias (+deg*dvec) (+ReLU), bf16 store, fused BN stats ----
    float B_[8], D_[8];
#pragma unroll
    for (int nt = 0; nt < 8; ++nt) {
        B_[nt] = bias[nt * 16 + ln];
        D_[nt] = NORM ? dvec[nt * 16 + ln] : 0.f;
    }
    float s8[8], q8[8];
#pragma unroll
    for (int nt = 0; nt < 8; ++nt) { s8[nt] = 0.f; q8[nt] = 0.f; }

#pragma unroll
    for (int mt = 0; mt < 2; ++mt) {
#pragma unroll
        for (int r = 0; r < 4; ++r) {
            int row = rowbase + mt * 16 + lg * 4 + r;
            if (row < M) {
                float dg = NORM ? degf[row] : 0.f;
#pragma unroll
                for (int nt = 0; nt < 8; ++nt) {
                    float v = acc[mt][nt][r] + B_[nt];
                    if (NORM) v += dg * D_[nt];
                    if (RELU) v = fmaxf(v, 0.f);
                    C[(size_t)row * NF + nt * 16 + ln] = (unsigned short)f2bf(v);
                    s8[nt] += v;
                    q8[nt] += v * v;
                }
            }
        }
    }

    float* ssum = sred;                // [16][128]
    float* ssq  = sred + 2048;
    const int rg = wid * 4 + lg;
#pragma unroll
    for (int nt = 0; nt < 8; ++nt) {
        ssum[rg * NF + nt * 16 + ln] = s8[nt];
        ssq [rg * NF + nt * 16 + ln] = q8[nt];
    }
    __syncthreads();
    if (tid < NF) {
        float s = 0.f, q = 0.f;
#pragma unroll
        for (int g = 0; g < 16; ++g) { s += ssum[g * NF + tid]; q += ssq[g * NF + tid]; }
        atomAddF(&gsum[tid], s);
        atomAddF(&gsq[tid], q);
    }
}

// Fold BN into affine: a = gamma*rsqrt(var+eps), c = beta - mean*a
__global__ __launch_bounds__(128) void bn_finalize(
    const float* __restrict__ gsum, const float* __restrict__ gsq,
    const float* __restrict__ gamma, const float* __restrict__ beta,
    float* __restrict__ a, float* __restrict__ c, int M)
{
    int k = threadIdx.x;
    float invM = 1.0f / (float)M;
    float mean = gsum[k] * invM;
    float var  = fmaxf(gsq[k] * invM - mean * mean, 0.f);
    float s    = gamma[k] / sqrtf(var + BN_EPS_C);
    a[k] = s;
    c[k] = beta[k] - mean * s;
}

// ---------------------------------------------------------------------------
// Pooling (bf16 input): batch is SORTED -> run-length accumulate.
// ---------------------------------------------------------------------------
__global__ __launch_bounds__(TPB) void pool_kernel(
    const unsigned short* __restrict__ h, const int* __restrict__ batch,
    float* __restrict__ pooled, float* __restrict__ counts, int M)
{
    int base = blockIdx.x * 128;
    int col  = threadIdx.x & 127;
    int half = threadIdx.x >> 7;
    int end  = min(base + 128, M);
    float acc = 0.f; int cnt = 0; int gcur = -1;
    for (int n = base + half; n < end; n += 2) {
        int g = batch[n];
        if (g != gcur) {
            if (gcur >= 0) {
                atomAddF(&pooled[(size_t)gcur * NF + col], acc);
                if (col == 0) atomAddF(&counts[gcur], (float)cnt);
            }
            acc = 0.f; cnt = 0; gcur = g;
        }
        acc += bf2f((short)h[(size_t)n * NF + col]);
        cnt += 1;
    }
    if (gcur >= 0) {
        atomAddF(&pooled[(size_t)gcur * NF + col], acc);
        if (col == 0) atomAddF(&counts[gcur], (float)cnt);
    }
}

__global__ __launch_bounds__(TPB) void final_kernel(
    const float* __restrict__ pooled, const float* __restrict__ counts,
    const float* __restrict__ a3, const float* __restrict__ c3,
    const float* __restrict__ Wlin, const float* __restrict__ blin,
    float* __restrict__ out, int G)
{
    int g = threadIdx.x;
    if (g >= G) return;
    float cntRaw = counts[g];
    float inv = 1.0f / fmaxf(cntRaw, 1.0f);
    float nonEmpty = cntRaw > 0.5f ? 1.0f : 0.0f;
    float acc0 = 0.f, acc1 = 0.f;
    for (int k = 0; k < NF; ++k) {
        float v = (a3[k] * pooled[(size_t)g * NF + k] * inv + c3[k]) * nonEmpty;
        acc0 += v * Wlin[k * 2 + 0];
        acc1 += v * Wlin[k * 2 + 1];
    }
    out[g * 2 + 0] = acc0 + blin[0];
    out[g * 2 + 1] = acc1 + blin[1];
}

// ---------------------------------------------------------------------------
extern "C" void kernel_launch(void* const* d_in, const int* in_sizes, int n_in,
                              void* d_out, int out_size, void* d_ws, size_t ws_size,
                              hipStream_t stream)
{
    const float* x     = (const float*)d_in[0];
    const int*   eidx  = (const int*)d_in[1];
    const int*   batch = (const int*)d_in[2];
    const float* W1r = (const float*)d_in[3],  *b1 = (const float*)d_in[4];
    const float* W1o = (const float*)d_in[5],  *g1 = (const float*)d_in[6],  *be1 = (const float*)d_in[7];
    const float* W2r = (const float*)d_in[8],  *b2 = (const float*)d_in[9];
    const float* W2o = (const float*)d_in[10], *g2 = (const float*)d_in[11], *be2 = (const float*)d_in[12];
    const float* W3r = (const float*)d_in[13], *b3 = (const float*)d_in[14];
    const float* W3o = (const float*)d_in[15], *g3 = (const float*)d_in[16], *be3 = (const float*)d_in[17];
    const float* Wlin = (const float*)d_in[18], *blin = (const float*)d_in[19];
    float* out = (float*)d_out;

    const int M = in_sizes[0] / NF;        // 100000 nodes
    const int E = in_sizes[1] / 2;         // 1.6M edges
    const int G = out_size / 2;            // 256 graphs
    const int* src = eidx;
    const int* dst = eidx + E;
    const int nbuck = (M + 511) >> BSH;

    const size_t NODEF = (size_t)M * NF;

    // ---- workspace layout (four bf16 node-feature planes) ----
    unsigned short* agg_hi = (unsigned short*)d_ws;       // NODEF bf16
    unsigned short* agg_lo = agg_hi + NODEF;              // NODEF bf16
    unsigned short* xb     = agg_lo + NODEF;              // NODEF bf16
    unsigned short* hb     = xb + NODEF;                  // NODEF bf16
    float* zf   = (float*)(hb + NODEF);            // zeroed float zone
    float* gsum1 = zf;        float* gsq1 = zf + 128;
    float* gsum2 = zf + 256;  float* gsq2 = zf + 384;
    float* gsum3 = zf + 512;  float* gsq3 = zf + 640;
    float* counts = zf + 768;                      // G
    float* pooled = counts + G;                    // G*NF
    int*   zi   = (int*)(pooled + (size_t)G * NF); // zeroed int zone (1024)
    int* bucket_cnt = zi;                          // 256
    int* bucket_cur = zi + 256;                    // 256
    int* boff       = zi + 512;                    // nbuck+1 (<=257)
    int* ziEnd      = zi + 1024;
    float* ac = (float*)ziEnd;                     // a/c per layer + fold outs
    float* a1 = ac;       float* c1 = ac + 128;
    float* a2 = ac + 256; float* c2 = ac + 384;
    float* a3 = ac + 512; float* c3 = ac + 640;
    float* bias2_2 = ac + 768;  float* dvec2 = ac + 896;
    float* bias2_3 = ac + 1024; float* dvec3 = ac + 1152;
    int* rowptr = (int*)(ac + 1280);               // M+1
    int* srcs   = rowptr + (M + 1);                // E
    float* degf = (float*)(srcs + E);              // M
    uintptr_t pp = ((uintptr_t)(degf + M) + 15) & ~(uintptr_t)15;
    int2* pairs = (int2*)pp;                       // E (CSR build only)
    // wt buffers UNION with pairs (pairs dead before wsplit/fold run)
    short* wt1_hi = (short*)pp;                    // each plane 128*256
    short* wt1_lo = wt1_hi + 32768;
    short* wt2_hi = wt1_hi + 65536;
    short* wt2_lo = wt1_hi + 98304;
    short* wt3_hi = wt1_hi + 131072;
    short* wt3_lo = wt1_hi + 163840;

    const int gridEP       = (E + PE_EPB - 1) / PE_EPB;
    const int gatherBlocks = (int)(((size_t)M * 64 + TPB - 1) / TPB);
    const int gemmBlocks   = (M + 127) / 128;
    const int poolBlocks   = (M + 127) / 128;
    const int cvtBlocks    = (int)((NODEF / 8 + TPB - 1) / TPB);

    // single memset: float zone + int zone
    size_t zbytes = (char*)ziEnd - (char*)zf;
    hipMemsetAsync(zf, 0, zbytes, stream);

    // ---- bucketed reverse-CSR build (dst-grouped), reused by all 3 layers
    bucket_count   <<<gridEP, TPB, 0, stream>>>(dst, bucket_cnt, E, nbuck);
    bucket_scan    <<<1, TPB, 0, stream>>>(bucket_cnt, boff, bucket_cur, nbuck, E);
    partition_edges<<<gridEP, TPB, 0, stream>>>(src, dst, bucket_cur, pairs, E, nbuck);
    bucket_build   <<<nbuck, TPB, 0, stream>>>(pairs, boff, rowptr, srcs, degf, M, E);

    // ---- x -> bf16
    cvt_bf16<<<cvtBlocks, TPB, 0, stream>>>(x, xb, (int)(NODEF / 8));

    // ---- layer 1 (no incoming norm)
    wsplit_kernel<<<128, 256, 0, stream>>>(W1r, W1o, wt1_hi, wt1_lo);
    gather_bf16<<<gatherBlocks, TPB, 0, stream>>>(xb, rowptr, srcs, agg_hi, agg_lo, M);
    gemm_mfma<true, false><<<gemmBlocks, TPB, 0, stream>>>(
        agg_hi, agg_lo, xb, wt1_hi, wt1_lo, b1, nullptr, nullptr, hb, gsum1, gsq1, M);
    bn_finalize<<<1, 128, 0, stream>>>(gsum1, gsq1, g1, be1, a1, c1, M);

    // ---- layer 2 (norm1 folded into weights)
    fold_kernel<<<128, 256, 0, stream>>>(a1, c1, W2r, W2o, b2, wt2_hi, wt2_lo, bias2_2, dvec2);
    gather_bf16<<<gatherBlocks, TPB, 0, stream>>>(hb, rowptr, srcs, agg_hi, agg_lo, M);
    gemm_mfma<true, true><<<gemmBlocks, TPB, 0, stream>>>(
        agg_hi, agg_lo, hb, wt2_hi, wt2_lo, bias2_2, dvec2, degf, hb, gsum2, gsq2, M);
    bn_finalize<<<1, 128, 0, stream>>>(gsum2, gsq2, g2, be2, a2, c2, M);

    // ---- layer 3 (no ReLU; norm2 folded into weights)
    fold_kernel<<<128, 256, 0, stream>>>(a2, c2, W3r, W3o, b3, wt3_hi, wt3_lo, bias2_3, dvec3);
    gather_bf16<<<gatherBlocks, TPB, 0, stream>>>(hb, rowptr, srcs, agg_hi, agg_lo, M);
    gemm_mfma<false, true><<<gemmBlocks, TPB, 0, stream>>>(
        agg_hi, agg_lo, hb, wt3_hi, wt3_lo, bias2_3, dvec3, degf, hb, gsum3, gsq3, M);
    bn_finalize<<<1, 128, 0, stream>>>(gsum3, gsq3, g3, be3, a3, c3, M);

    // ---- pool + classify (norm3 applied on pooled means)
    pool_kernel<<<poolBlocks, TPB, 0, stream>>>(hb, batch, pooled, counts, M);
    final_kernel<<<1, TPB, 0, stream>>>(pooled, counts, a3, c3, Wlin, blin, out, G);
}

// Round 8
// 554.297 us; speedup vs baseline: 8.6950x; 1.2444x over previous
//
#include <hip/hip_runtime.h>
#include <math.h>
#include <stdint.h>

#define TPB 256
#define NF 128          // feature width (all layers)
#define BN_EPS_C 1e-5f
#define BSH 9           // bucket shift: 512 nodes per bucket
#define PE_EPB 4096     // edges per block in count/partition

typedef __attribute__((ext_vector_type(8))) short bf16x8;   // 8 bf16 (4 VGPRs)
typedef __attribute__((ext_vector_type(4))) float f32x4;    // 4 fp32

// ---------------------------------------------------------------------------
__device__ __forceinline__ void atomAddF(float* p, float v) {
    unsafeAtomicAdd(p, v);
}

// fp32 <-> bf16 (RNE), bit-level
__device__ __forceinline__ short f2bf(float f) {
    unsigned u = __float_as_uint(f);
    unsigned r = (u + 0x7FFFu + ((u >> 16) & 1u)) >> 16;
    return (short)r;
}
__device__ __forceinline__ float bf2f(short b) {
    return __uint_as_float(((unsigned)(unsigned short)b) << 16);
}
__device__ __forceinline__ float bflo(unsigned u) { return __uint_as_float(u << 16); }
__device__ __forceinline__ float bfhi(unsigned u) { return __uint_as_float(u & 0xffff0000u); }
__device__ __forceinline__ unsigned packbf(float lo, float hi) {
    return (unsigned)(unsigned short)f2bf(lo) | ((unsigned)(unsigned short)f2bf(hi) << 16);
}

// async 16B global -> LDS DMA (global_load_lds dwordx4)
__device__ __forceinline__ void async_copy16u(const unsigned short* g, unsigned short* l) {
    __builtin_amdgcn_global_load_lds(
        (const __attribute__((address_space(1))) unsigned int*)g,
        (__attribute__((address_space(3))) unsigned int*)l, 16, 0, 0);
}

// ===========================================================================
// Bucketed CSR build (dst-grouped). Per-bucket srcs region is ~32KB
// (L2-resident) so scatter writes don't thrash HBM.
// ===========================================================================
__global__ __launch_bounds__(TPB) void bucket_count(
    const int* __restrict__ dst, int* __restrict__ bucket_cnt, int E, int nbuck)
{
    __shared__ int h[256];
    h[threadIdx.x] = 0;
    __syncthreads();
    int base = blockIdx.x * PE_EPB;
    int lim = min(base + PE_EPB, E);
    for (int i = base + threadIdx.x; i < lim; i += 256)
        atomicAdd(&h[dst[i] >> BSH], 1);
    __syncthreads();
    if (threadIdx.x < nbuck && h[threadIdx.x])
        atomicAdd(&bucket_cnt[threadIdx.x], h[threadIdx.x]);
}

__global__ __launch_bounds__(TPB) void bucket_scan(
    const int* __restrict__ bucket_cnt, int* __restrict__ boff,
    int* __restrict__ bucket_cur, int nbuck, int E)
{
    __shared__ int s[256];
    int t = threadIdx.x;
    int v = (t < nbuck) ? bucket_cnt[t] : 0;
    s[t] = v;
    __syncthreads();
    for (int off = 1; off < 256; off <<= 1) {
        int x = (t >= off) ? s[t - off] : 0;
        __syncthreads();
        s[t] += x;
        __syncthreads();
    }
    int excl = s[t] - v;
    if (t < nbuck) { boff[t] = excl; bucket_cur[t] = excl; }
    if (t == 0) boff[nbuck] = E;
}

__global__ __launch_bounds__(TPB) void partition_edges(
    const int* __restrict__ src, const int* __restrict__ dst,
    int* __restrict__ bucket_cur, int2* __restrict__ pairs, int E, int nbuck)
{
    __shared__ int cnt[256];
    __shared__ int gbase[256];
    int t = threadIdx.x;
    cnt[t] = 0;
    __syncthreads();
    int base = blockIdx.x * PE_EPB;
    int myb[16], myrank[16], mys[16], myd[16];
#pragma unroll
    for (int j = 0; j < 16; ++j) {
        int i = base + j * 256 + t;
        if (i < E) {
            int d = dst[i];
            int b = d >> BSH;
            myb[j] = b; myd[j] = d; mys[j] = src[i];
            myrank[j] = atomicAdd(&cnt[b], 1);
        } else myb[j] = -1;
    }
    __syncthreads();
    if (t < nbuck && cnt[t]) gbase[t] = atomicAdd(&bucket_cur[t], cnt[t]);
    __syncthreads();
#pragma unroll
    for (int j = 0; j < 16; ++j)
        if (myb[j] >= 0)
            pairs[gbase[myb[j]] + myrank[j]] = make_int2(mys[j], myd[j]);
}

__global__ __launch_bounds__(TPB) void bucket_build(
    const int2* __restrict__ pairs, const int* __restrict__ boff,
    int* __restrict__ rowptr, int* __restrict__ srcs,
    float* __restrict__ degf, int M, int E)
{
    __shared__ int ldeg[512];
    __shared__ int lsum[256];
    int b = blockIdx.x;
    int t = threadIdx.x;
    int n0 = b << BSH;
    int nn = min(512, M - n0);
    int p0 = boff[b], p1 = boff[b + 1];
    ldeg[t] = 0; ldeg[t + 256] = 0;
    __syncthreads();
    for (int i = p0 + t; i < p1; i += 256)
        atomicAdd(&ldeg[pairs[i].y - n0], 1);
    __syncthreads();
    int a0 = ldeg[2 * t], a1 = ldeg[2 * t + 1];
    lsum[t] = a0 + a1;
    __syncthreads();
    for (int off = 1; off < 256; off <<= 1) {
        int x = (t >= off) ? lsum[t - off] : 0;
        __syncthreads();
        lsum[t] += x;
        __syncthreads();
    }
    int excl = lsum[t] - (a0 + a1);
    ldeg[2 * t]     = p0 + excl;            // becomes scatter cursor
    ldeg[2 * t + 1] = p0 + excl + a0;
    if (2 * t < nn)     { rowptr[n0 + 2 * t]     = p0 + excl;      degf[n0 + 2 * t]     = (float)a0; }
    if (2 * t + 1 < nn) { rowptr[n0 + 2 * t + 1] = p0 + excl + a0; degf[n0 + 2 * t + 1] = (float)a1; }
    if (b == 0 && t == 0) rowptr[M] = E;
    __syncthreads();
    for (int i = p0 + t; i < p1; i += 256) {
        int2 pr = pairs[i];
        int pos = atomicAdd(&ldeg[pr.y - n0], 1);
        srcs[pos] = pr.x;
    }
}

// ===========================================================================
// x -> bf16 convert (once)
// ===========================================================================
__global__ __launch_bounds__(TPB) void cvt_bf16(
    const float* __restrict__ x, unsigned short* __restrict__ xb, int n8)
{
    int i = blockIdx.x * TPB + threadIdx.x;
    if (i >= n8) return;
    const f32x4* p = (const f32x4*)(x + (size_t)i * 8);
    f32x4 v0 = p[0], v1 = p[1];
    uint4 o;
    o.x = packbf(v0.x, v0.y); o.y = packbf(v0.z, v0.w);
    o.z = packbf(v1.x, v1.y); o.w = packbf(v1.z, v1.w);
    *(uint4*)(xb + (size_t)i * 8) = o;
}

// ===========================================================================
// Gather aggregation (bf16 rows, fp32 accumulate), output SPLIT into two
// bf16 planes (hi = RNE(v), lo = RNE(v-hi)).
// ===========================================================================
__device__ __forceinline__ void acc8(float* a, uint4 r) {
    a[0] += bflo(r.x); a[1] += bfhi(r.x);
    a[2] += bflo(r.y); a[3] += bfhi(r.y);
    a[4] += bflo(r.z); a[5] += bfhi(r.z);
    a[6] += bflo(r.w); a[7] += bfhi(r.w);
}
__device__ __forceinline__ void acc8m(float* a, uint4 r, float m) {
    a[0] = fmaf(m, bflo(r.x), a[0]); a[1] = fmaf(m, bfhi(r.x), a[1]);
    a[2] = fmaf(m, bflo(r.y), a[2]); a[3] = fmaf(m, bfhi(r.y), a[3]);
    a[4] = fmaf(m, bflo(r.z), a[4]); a[5] = fmaf(m, bfhi(r.z), a[5]);
    a[6] = fmaf(m, bflo(r.w), a[6]); a[7] = fmaf(m, bfhi(r.w), a[7]);
}

__global__ __launch_bounds__(TPB) void gather_bf16(
    const unsigned short* __restrict__ hb, const int* __restrict__ rowptr,
    const int* __restrict__ srcs,
    unsigned short* __restrict__ agg_hi, unsigned short* __restrict__ agg_lo, int M)
{
    int wid = (blockIdx.x * TPB + threadIdx.x) >> 6;
    if (wid >= M) return;
    int lane = threadIdx.x & 63;
    int grp  = lane >> 4;
    int li   = lane & 15;
    int start = rowptr[wid], end = rowptr[wid + 1];

    float a0[8] = {0, 0, 0, 0, 0, 0, 0, 0};
    float a1[8] = {0, 0, 0, 0, 0, 0, 0, 0};
    int e = start;
    for (; e + 7 < end; e += 8) {
        int s0 = srcs[e + grp];
        int s1 = srcs[e + 4 + grp];
        uint4 r0 = *(const uint4*)(hb + (size_t)s0 * NF + li * 8);
        uint4 r1 = *(const uint4*)(hb + (size_t)s1 * NF + li * 8);
        acc8(a0, r0);
        acc8(a1, r1);
    }
    for (; e < end; e += 4) {
        int idx = e + grp;
        int s = srcs[min(idx, end - 1)];
        uint4 r = *(const uint4*)(hb + (size_t)s * NF + li * 8);
        float m = (idx < end) ? 1.0f : 0.0f;
        acc8m(a0, r, m);
    }
#pragma unroll
    for (int j = 0; j < 8; ++j) a0[j] += a1[j];
#pragma unroll
    for (int j = 0; j < 8; ++j) a0[j] += __shfl_xor(a0[j], 16);
#pragma unroll
    for (int j = 0; j < 8; ++j) a0[j] += __shfl_xor(a0[j], 32);
    if (lane < 16) {
        float h[8], l[8];
#pragma unroll
        for (int j = 0; j < 8; ++j) {
            h[j] = bf2f(f2bf(a0[j]));
            l[j] = a0[j] - h[j];
        }
        uint4 oh, ol;
        oh.x = packbf(h[0], h[1]); oh.y = packbf(h[2], h[3]);
        oh.z = packbf(h[4], h[5]); oh.w = packbf(h[6], h[7]);
        ol.x = packbf(l[0], l[1]); ol.y = packbf(l[2], l[3]);
        ol.z = packbf(l[4], l[5]); ol.w = packbf(l[6], l[7]);
        *(uint4*)(agg_hi + (size_t)wid * NF + li * 8) = oh;
        *(uint4*)(agg_lo + (size_t)wid * NF + li * 8) = ol;
    }
}

// ===========================================================================
// W pack layout (per layer): 8 chunks of 16 KB, DMA-linear.
// chunk kc holds concat-k range [kc*32, kc*32+32) for all 128 n.
// Within chunk: n row = 128 B = 8 slots of 16 B; logical slot 0..3 = hi
// (k-group lg), 4..7 = lo; PHYSICAL slot = logical ^ (n&7)  (bank swizzle,
// baked at pack time so GEMM DMA is a pure linear copy and ds_read_b128
// fragment reads are 2-way-conflict-only = free).
// ===========================================================================
__device__ __forceinline__ void wpack_store(
    unsigned short* __restrict__ wpk, int n, int k, float w)
{
    short h = f2bf(w);
    short l = f2bf(w - bf2f(h));
    int kc = k >> 5, grp = (k >> 3) & 3, el = k & 7;
    int base = kc * 8192 + n * 64;
    wpk[base + ((grp      ) ^ (n & 7)) * 8 + el] = (unsigned short)h;
    wpk[base + ((grp ^ 4) ^ (n & 7)) * 8 + el] = (unsigned short)l;
}

// Layer-1 W prep (no norm): transpose + concat + split + pack.
__global__ __launch_bounds__(256) void wsplit_kernel(
    const float* __restrict__ Wr, const float* __restrict__ Wo,
    unsigned short* __restrict__ wpk)
{
    int n = blockIdx.x;      // 0..127
    int k = threadIdx.x;     // 0..255
    float v = (k < NF) ? Wr[k * NF + n] : Wo[(k - NF) * NF + n];
    wpack_store(wpk, n, k, v);
}

// Fold BN affine (a,c) of the previous layer into this layer's weights.
__global__ __launch_bounds__(256) void fold_kernel(
    const float* __restrict__ a, const float* __restrict__ c,
    const float* __restrict__ Wr, const float* __restrict__ Wo,
    const float* __restrict__ b,
    unsigned short* __restrict__ wpk,
    float* __restrict__ bias2, float* __restrict__ dvec)
{
    __shared__ float red[256];
    int n = blockIdx.x;
    int k = threadIdx.x;
    float w, contrib;
    if (k < NF) { w = Wr[k * NF + n];          contrib = c[k] * w;       w *= a[k]; }
    else        { int kk = k - NF; w = Wo[kk * NF + n]; contrib = c[kk] * w; w *= a[kk]; }
    wpack_store(wpk, n, k, w);
    red[k] = contrib;
    __syncthreads();
    for (int off = 64; off >= 1; off >>= 1) {
        if ((k & 127) < off) red[k] += red[k + off];
        __syncthreads();
    }
    if (k == 0)   dvec[n]  = red[0];
    if (k == 128) bias2[n] = b[n] + red[128];
}

// ===========================================================================
// MFMA dual GEMM v5 — W LDS-staged (shared x4 waves), A direct + reg prefetch:
//   C = Shi/Slo @ Wagg^T (3-term) + h @ Wroot^T (2-term)
//       + bias (+deg*dvec) (+ReLU) (+fused BN stats)
// Per kc: 16 KB W chunk DMA'd to LDS (global_load_lds w16, 2-barrier m97
// pattern); W frags via ds_read_b128 (2-way conflicts only); A frags are
// per-lane bf16x8 global loads prefetched one chunk ahead into registers.
// W global loads per lane: 128 (R7) -> 0. MFMA order identical to R7.
// ===========================================================================
template<bool RELU, bool NORM>
__global__ __launch_bounds__(TPB) void gemm_mfma(
    const unsigned short* __restrict__ Ahi, const unsigned short* __restrict__ Alo,
    const unsigned short* Ax,                                  // may alias C
    const unsigned short* __restrict__ wpk,
    const float* __restrict__ bias, const float* __restrict__ dvec,
    const float* __restrict__ degf, unsigned short* C,
    float* __restrict__ gsum, float* __restrict__ gsq, int M)
{
    __shared__ unsigned short sW[8192];    // 16 KB W chunk; reused for stats

    const int tid  = threadIdx.x;
    const int wid  = tid >> 6;
    const int lane = tid & 63;
    const int lg   = lane >> 4;        // quad 0..3
    const int ln   = lane & 15;
    const int rowbase = blockIdx.x * 128 + wid * 32;

    f32x4 acc[2][8];
#pragma unroll
    for (int i = 0; i < 2; ++i)
#pragma unroll
        for (int j = 0; j < 8; ++j) acc[i][j] = (f32x4){0.f, 0.f, 0.f, 0.f};

    size_t aoff[2];
#pragma unroll
    for (int mt = 0; mt < 2; ++mt)
        aoff[mt] = (size_t)min(rowbase + mt * 16 + ln, M - 1) * NF + lg * 8;

    // DMA chunk 0 + preload agg kc=0 A frags
    {
#pragma unroll
        for (int it = 0; it < 4; ++it) {
            int seg = it * 256 + tid;
            async_copy16u(wpk + seg * 8, sW + seg * 8);
        }
    }
    bf16x8 aH[2], aL[2], nH[2], nL[2];
#pragma unroll
    for (int mt = 0; mt < 2; ++mt) {
        aH[mt] = *(const bf16x8*)(Ahi + aoff[mt]);
        aL[mt] = *(const bf16x8*)(Alo + aoff[mt]);
    }

#pragma unroll
    for (int kc = 0; kc < 8; ++kc) {
        __syncthreads();               // chunk kc resident in sW

        // ---- prefetch next chunk's A fragments into registers
        if (kc < 3) {
#pragma unroll
            for (int mt = 0; mt < 2; ++mt) {
                nH[mt] = *(const bf16x8*)(Ahi + aoff[mt] + (kc + 1) * 32);
                nL[mt] = *(const bf16x8*)(Alo + aoff[mt] + (kc + 1) * 32);
            }
        } else if (kc < 7) {           // next is root chunk (kc+1-4)*32
#pragma unroll
            for (int mt = 0; mt < 2; ++mt)
                nH[mt] = *(const bf16x8*)(Ax + aoff[mt] + (kc - 3) * 32);
        }

        // ---- compute on chunk kc (W from LDS)
#pragma unroll
        for (int nt = 0; nt < 8; ++nt) {
            int n = nt * 16 + ln;
            int boff = n * 64 + ((lg ^ (n & 7)) << 3);
            bf16x8 bhi = *(const bf16x8*)(sW + boff);
            bf16x8 blo = *(const bf16x8*)(sW + (boff ^ 32));
            if (kc < 4) {
#pragma unroll
                for (int mt = 0; mt < 2; ++mt) {
                    acc[mt][nt] = __builtin_amdgcn_mfma_f32_16x16x32_bf16(aH[mt], bhi, acc[mt][nt], 0, 0, 0);
                    acc[mt][nt] = __builtin_amdgcn_mfma_f32_16x16x32_bf16(aL[mt], bhi, acc[mt][nt], 0, 0, 0);
                    acc[mt][nt] = __builtin_amdgcn_mfma_f32_16x16x32_bf16(aH[mt], blo, acc[mt][nt], 0, 0, 0);
                }
            } else {
#pragma unroll
                for (int mt = 0; mt < 2; ++mt) {
                    acc[mt][nt] = __builtin_amdgcn_mfma_f32_16x16x32_bf16(aH[mt], bhi, acc[mt][nt], 0, 0, 0);
                    acc[mt][nt] = __builtin_amdgcn_mfma_f32_16x16x32_bf16(aH[mt], blo, acc[mt][nt], 0, 0, 0);
                }
            }
        }

        __syncthreads();               // all waves done reading chunk kc
        if (kc < 7) {
            const unsigned short* src = wpk + (kc + 1) * 8192;
#pragma unroll
            for (int it = 0; it < 4; ++it) {
                int seg = it * 256 + tid;
                async_copy16u(src + seg * 8, sW + seg * 8);
            }
        }
#pragma unroll
        for (int mt = 0; mt < 2; ++mt) { aH[mt] = nH[mt]; aL[mt] = nL[mt]; }
    }

    // ---- epilogue: bias (+deg*dvec) (+ReLU), bf16 store, fused BN stats ----
    float B_[8], D_[8];
#pragma unroll
    for (int nt = 0; nt < 8; ++nt) {
        B_[nt] = bias[nt * 16 + ln];
        D_[nt] = NORM ? dvec[nt * 16 + ln] : 0.f;
    }
    float s8[8], q8[8];
#pragma unroll
    for (int nt = 0; nt < 8; ++nt) { s8[nt] = 0.f; q8[nt] = 0.f; }

#pragma unroll
    for (int mt = 0; mt < 2; ++mt) {
#pragma unroll
        for (int r = 0; r < 4; ++r) {
            int row = rowbase + mt * 16 + lg * 4 + r;
            if (row < M) {
                float dg = NORM ? degf[row] : 0.f;
#pragma unroll
                for (int nt = 0; nt < 8; ++nt) {
                    float v = acc[mt][nt][r] + B_[nt];
                    if (NORM) v += dg * D_[nt];
                    if (RELU) v = fmaxf(v, 0.f);
                    C[(size_t)row * NF + nt * 16 + ln] = (unsigned short)f2bf(v);
                    s8[nt] += v;
                    q8[nt] += v * v;
                }
            }
        }
    }

    __syncthreads();                   // done with sW as W buffer
    float* ssum = (float*)sW;          // [16][128]
    float* ssq  = ssum + 2048;
    const int rg = wid * 4 + lg;
#pragma unroll
    for (int nt = 0; nt < 8; ++nt) {
        ssum[rg * NF + nt * 16 + ln] = s8[nt];
        ssq [rg * NF + nt * 16 + ln] = q8[nt];
    }
    __syncthreads();
    if (tid < NF) {
        float s = 0.f, q = 0.f;
#pragma unroll
        for (int g = 0; g < 16; ++g) { s += ssum[g * NF + tid]; q += ssq[g * NF + tid]; }
        atomAddF(&gsum[tid], s);
        atomAddF(&gsq[tid], q);
    }
}

// Fold BN into affine: a = gamma*rsqrt(var+eps), c = beta - mean*a
__global__ __launch_bounds__(128) void bn_finalize(
    const float* __restrict__ gsum, const float* __restrict__ gsq,
    const float* __restrict__ gamma, const float* __restrict__ beta,
    float* __restrict__ a, float* __restrict__ c, int M)
{
    int k = threadIdx.x;
    float invM = 1.0f / (float)M;
    float mean = gsum[k] * invM;
    float var  = fmaxf(gsq[k] * invM - mean * mean, 0.f);
    float s    = gamma[k] / sqrtf(var + BN_EPS_C);
    a[k] = s;
    c[k] = beta[k] - mean * s;
}

// ---------------------------------------------------------------------------
// Pooling (bf16 input): batch is SORTED -> run-length accumulate.
// ---------------------------------------------------------------------------
__global__ __launch_bounds__(TPB) void pool_kernel(
    const unsigned short* __restrict__ h, const int* __restrict__ batch,
    float* __restrict__ pooled, float* __restrict__ counts, int M)
{
    int base = blockIdx.x * 128;
    int col  = threadIdx.x & 127;
    int half = threadIdx.x >> 7;
    int end  = min(base + 128, M);
    float acc = 0.f; int cnt = 0; int gcur = -1;
    for (int n = base + half; n < end; n += 2) {
        int g = batch[n];
        if (g != gcur) {
            if (gcur >= 0) {
                atomAddF(&pooled[(size_t)gcur * NF + col], acc);
                if (col == 0) atomAddF(&counts[gcur], (float)cnt);
            }
            acc = 0.f; cnt = 0; gcur = g;
        }
        acc += bf2f((short)h[(size_t)n * NF + col]);
        cnt += 1;
    }
    if (gcur >= 0) {
        atomAddF(&pooled[(size_t)gcur * NF + col], acc);
        if (col == 0) atomAddF(&counts[gcur], (float)cnt);
    }
}

__global__ __launch_bounds__(TPB) void final_kernel(
    const float* __restrict__ pooled, const float* __restrict__ counts,
    const float* __restrict__ a3, const float* __restrict__ c3,
    const float* __restrict__ Wlin, const float* __restrict__ blin,
    float* __restrict__ out, int G)
{
    int g = threadIdx.x;
    if (g >= G) return;
    float cntRaw = counts[g];
    float inv = 1.0f / fmaxf(cntRaw, 1.0f);
    float nonEmpty = cntRaw > 0.5f ? 1.0f : 0.0f;
    float acc0 = 0.f, acc1 = 0.f;
    for (int k = 0; k < NF; ++k) {
        float v = (a3[k] * pooled[(size_t)g * NF + k] * inv + c3[k]) * nonEmpty;
        acc0 += v * Wlin[k * 2 + 0];
        acc1 += v * Wlin[k * 2 + 1];
    }
    out[g * 2 + 0] = acc0 + blin[0];
    out[g * 2 + 1] = acc1 + blin[1];
}

// ---------------------------------------------------------------------------
extern "C" void kernel_launch(void* const* d_in, const int* in_sizes, int n_in,
                              void* d_out, int out_size, void* d_ws, size_t ws_size,
                              hipStream_t stream)
{
    const float* x     = (const float*)d_in[0];
    const int*   eidx  = (const int*)d_in[1];
    const int*   batch = (const int*)d_in[2];
    const float* W1r = (const float*)d_in[3],  *b1 = (const float*)d_in[4];
    const float* W1o = (const float*)d_in[5],  *g1 = (const float*)d_in[6],  *be1 = (const float*)d_in[7];
    const float* W2r = (const float*)d_in[8],  *b2 = (const float*)d_in[9];
    const float* W2o = (const float*)d_in[10], *g2 = (const float*)d_in[11], *be2 = (const float*)d_in[12];
    const float* W3r = (const float*)d_in[13], *b3 = (const float*)d_in[14];
    const float* W3o = (const float*)d_in[15], *g3 = (const float*)d_in[16], *be3 = (const float*)d_in[17];
    const float* Wlin = (const float*)d_in[18], *blin = (const float*)d_in[19];
    float* out = (float*)d_out;

    const int M = in_sizes[0] / NF;        // 100000 nodes
    const int E = in_sizes[1] / 2;         // 1.6M edges
    const int G = out_size / 2;            // 256 graphs
    const int* src = eidx;
    const int* dst = eidx + E;
    const int nbuck = (M + 511) >> BSH;

    const size_t NODEF = (size_t)M * NF;

    // ---- workspace layout (four bf16 node-feature planes) ----
    unsigned short* agg_hi = (unsigned short*)d_ws;       // NODEF bf16
    unsigned short* agg_lo = agg_hi + NODEF;              // NODEF bf16
    unsigned short* xb     = agg_lo + NODEF;              // NODEF bf16
    unsigned short* hb     = xb + NODEF;                  // NODEF bf16
    float* zf   = (float*)(hb + NODEF);            // zeroed float zone
    float* gsum1 = zf;        float* gsq1 = zf + 128;
    float* gsum2 = zf + 256;  float* gsq2 = zf + 384;
    float* gsum3 = zf + 512;  float* gsq3 = zf + 640;
    float* counts = zf + 768;                      // G
    float* pooled = counts + G;                    // G*NF
    int*   zi   = (int*)(pooled + (size_t)G * NF); // zeroed int zone (1024)
    int* bucket_cnt = zi;                          // 256
    int* bucket_cur = zi + 256;                    // 256
    int* boff       = zi + 512;                    // nbuck+1 (<=257)
    int* ziEnd      = zi + 1024;
    float* ac = (float*)ziEnd;                     // a/c per layer + fold outs
    float* a1 = ac;       float* c1 = ac + 128;
    float* a2 = ac + 256; float* c2 = ac + 384;
    float* a3 = ac + 512; float* c3 = ac + 640;
    float* bias2_2 = ac + 768;  float* dvec2 = ac + 896;
    float* bias2_3 = ac + 1024; float* dvec3 = ac + 1152;
    int* rowptr = (int*)(ac + 1280);               // M+1
    int* srcs   = rowptr + (M + 1);                // E
    float* degf = (float*)(srcs + E);              // M
    uintptr_t pp = ((uintptr_t)(degf + M) + 15) & ~(uintptr_t)15;
    int2* pairs = (int2*)pp;                       // E (CSR build only)
    // packed-W buffers UNION with pairs (pairs dead before wsplit/fold run)
    unsigned short* wpk1 = (unsigned short*)pp;    // 65536 each (128 KB)
    unsigned short* wpk2 = wpk1 + 65536;
    unsigned short* wpk3 = wpk2 + 65536;

    const int gridEP       = (E + PE_EPB - 1) / PE_EPB;
    const int gatherBlocks = (int)(((size_t)M * 64 + TPB - 1) / TPB);
    const int gemmBlocks   = (M + 127) / 128;
    const int poolBlocks   = (M + 127) / 128;
    const int cvtBlocks    = (int)((NODEF / 8 + TPB - 1) / TPB);

    // single memset: float zone + int zone
    size_t zbytes = (char*)ziEnd - (char*)zf;
    hipMemsetAsync(zf, 0, zbytes, stream);

    // ---- bucketed reverse-CSR build (dst-grouped), reused by all 3 layers
    bucket_count   <<<gridEP, TPB, 0, stream>>>(dst, bucket_cnt, E, nbuck);
    bucket_scan    <<<1, TPB, 0, stream>>>(bucket_cnt, boff, bucket_cur, nbuck, E);
    partition_edges<<<gridEP, TPB, 0, stream>>>(src, dst, bucket_cur, pairs, E, nbuck);
    bucket_build   <<<nbuck, TPB, 0, stream>>>(pairs, boff, rowptr, srcs, degf, M, E);

    // ---- x -> bf16
    cvt_bf16<<<cvtBlocks, TPB, 0, stream>>>(x, xb, (int)(NODEF / 8));

    // ---- layer 1 (no incoming norm)
    wsplit_kernel<<<128, 256, 0, stream>>>(W1r, W1o, wpk1);
    gather_bf16<<<gatherBlocks, TPB, 0, stream>>>(xb, rowptr, srcs, agg_hi, agg_lo, M);
    gemm_mfma<true, false><<<gemmBlocks, TPB, 0, stream>>>(
        agg_hi, agg_lo, xb, wpk1, b1, nullptr, nullptr, hb, gsum1, gsq1, M);
    bn_finalize<<<1, 128, 0, stream>>>(gsum1, gsq1, g1, be1, a1, c1, M);

    // ---- layer 2 (norm1 folded into weights)
    fold_kernel<<<128, 256, 0, stream>>>(a1, c1, W2r, W2o, b2, wpk2, bias2_2, dvec2);
    gather_bf16<<<gatherBlocks, TPB, 0, stream>>>(hb, rowptr, srcs, agg_hi, agg_lo, M);
    gemm_mfma<true, true><<<gemmBlocks, TPB, 0, stream>>>(
        agg_hi, agg_lo, hb, wpk2, bias2_2, dvec2, degf, hb, gsum2, gsq2, M);
    bn_finalize<<<1, 128, 0, stream>>>(gsum2, gsq2, g2, be2, a2, c2, M);

    // ---- layer 3 (no ReLU; norm2 folded into weights)
    fold_kernel<<<128, 256, 0, stream>>>(a2, c2, W3r, W3o, b3, wpk3, bias2_3, dvec3);
    gather_bf16<<<gatherBlocks, TPB, 0, stream>>>(hb, rowptr, srcs, agg_hi, agg_lo, M);
    gemm_mfma<false, true><<<gemmBlocks, TPB, 0, stream>>>(
        agg_hi, agg_lo, hb, wpk3, bias2_3, dvec3, degf, hb, gsum3, gsq3, M);
    bn_finalize<<<1, 128, 0, stream>>>(gsum3, gsq3, g3, be3, a3, c3, M);

    // ---- pool + classify (norm3 applied on pooled means)
    pool_kernel<<<poolBlocks, TPB, 0, stream>>>(hb, batch, pooled, counts, M);
    final_kernel<<<1, TPB, 0, stream>>>(pooled, counts, a3, c3, Wlin, blin, out, G);
}